// Round 1
// baseline (405.219 us; speedup 1.0000x reference)
//
#include <hip/hip_runtime.h>
#include <hip/hip_bf16.h>

#define L_SEQ 2048
#define D_MODEL 512
#define NH 8
#define HD 64
#define EPSF 1e-5f

typedef __attribute__((ext_vector_type(8))) short short8;
typedef __attribute__((ext_vector_type(4))) float f32x4;

// ---------------- fp32 -> bf16 convert ----------------
__global__ void cvt_bf16_kernel(const float* __restrict__ s, __hip_bfloat16* __restrict__ d, int n) {
  for (int i = blockIdx.x * blockDim.x + threadIdx.x; i < n; i += gridDim.x * blockDim.x)
    d[i] = __float2bfloat16(s[i]);
}

// ---------------- GEMM: O = A @ W^T + bias (A:[M,K], W:[N,K] bf16, O fp32) ----------------
// MFMA 16x16x32 bf16. A-frag: A[m=lane&15][k=quad*8+j]; B-frag: W[n=lane&15][k=quad*8+j]
// C/D: col(n)=lane&15, row(m)=quad*4+r   (gfx950-verified mapping)
// TRANS=1 writes O transposed as [N][M] (channel-major), used for k,v,filters.
template<int TRANS>
__global__ __launch_bounds__(256) void gemm_bt_kernel(const __hip_bfloat16* __restrict__ A,
    const __hip_bfloat16* __restrict__ W, const float* __restrict__ bias,
    float* __restrict__ O, int M, int N, int K)
{
  int lane = threadIdx.x & 63;
  int wave = threadIdx.x >> 6;
  int m0 = blockIdx.x * 64 + wave * 16;
  int n0 = blockIdx.y * 64;
  int lrow = lane & 15, quad = lane >> 4;
  const __hip_bfloat16* Ap = A + (size_t)(m0 + lrow) * K + quad * 8;
  const __hip_bfloat16* Wp = W + (size_t)(n0 + lrow) * K + quad * 8;
  f32x4 acc[4] = {};
  for (int k0 = 0; k0 < K; k0 += 32) {
    short8 a = *(const short8*)(Ap + k0);
#pragma unroll
    for (int j = 0; j < 4; ++j) {
      short8 b = *(const short8*)(Wp + k0 + (size_t)j * 16 * K);
      acc[j] = __builtin_amdgcn_mfma_f32_16x16x32_bf16(a, b, acc[j], 0, 0, 0);
    }
  }
#pragma unroll
  for (int j = 0; j < 4; ++j) {
    int n = n0 + j * 16 + lrow;
    float bv = bias[n];
    if (TRANS) {
      float4 o;
      o.x = acc[j][0] + bv; o.y = acc[j][1] + bv; o.z = acc[j][2] + bv; o.w = acc[j][3] + bv;
      *(float4*)(O + (size_t)n * M + m0 + quad * 4) = o;
    } else {
#pragma unroll
      for (int r = 0; r < 4; ++r)
        O[(size_t)(m0 + quad * 4 + r) * N + n] = acc[j][r] + bv;
    }
  }
}

// ---------------- in-place L2 norm over head-dim (64) on channel-major [512][2048] ----------------
__global__ __launch_bounds__(256) void l2norm_kernel(float* __restrict__ kT, float* __restrict__ vT) {
  float* base = (blockIdx.z ? vT : kT) + (size_t)blockIdx.y * HD * L_SEQ + blockIdx.x * 256 + threadIdx.x;
  float vv[HD];
  float ss = 0.f;
#pragma unroll
  for (int d = 0; d < HD; ++d) { vv[d] = base[(size_t)d * L_SEQ]; ss = fmaf(vv[d], vv[d], ss); }
  float sc = 1.f / fmaxf(sqrtf(ss), EPSF);
#pragma unroll
  for (int d = 0; d < HD; ++d) base[(size_t)d * L_SEQ] = vv[d] * sc;
}

// ---------------- causal conv along L: out[c,l] = sum_{s<=l} F[c,l-s]*u[c,s] ----------------
// channel-major [512][2048]. Block: 16 channels x two 128-l tiles (paired lb & 15-lb for balance).
__global__ __launch_bounds__(256) void conv_kernel(const float* __restrict__ uK, const float* __restrict__ uV,
    const float* __restrict__ F, float* __restrict__ oK, float* __restrict__ oV)
{
  __shared__ float u_lds[16][132];
  __shared__ float f_lds[16][260];
  const float* u = blockIdx.z ? uV : uK;
  float* o = blockIdx.z ? oV : oK;
  int cbase = blockIdx.x * 16;
  int cl = threadIdx.x >> 4;
  int li = threadIdx.x & 15;
  for (int half = 0; half < 2; ++half) {
    int lt = half ? (15 - (int)blockIdx.y) : (int)blockIdx.y;
    float acc[8] = {0.f, 0.f, 0.f, 0.f, 0.f, 0.f, 0.f, 0.f};
    for (int st = 0; st <= lt; ++st) {
#pragma unroll
      for (int k = 0; k < 8; ++k) {
        int f = threadIdx.x + k * 256;
        u_lds[f >> 7][f & 127] = u[(size_t)(cbase + (f >> 7)) * L_SEQ + st * 128 + (f & 127)];
      }
      int fb = (lt - st) * 128 - 127;
#pragma unroll
      for (int k = 0; k < 16; ++k) {
        int f = threadIdx.x + k * 256;
        int c = f >> 8, t = f & 255;
        int gi = fb + t;
        f_lds[c][t] = (gi >= 0 && gi < L_SEQ) ? F[(size_t)(cbase + c) * L_SEQ + gi] : 0.f;
      }
      __syncthreads();
      const float4* u4 = (const float4*)(&u_lds[cl][0]);
      const float4* f4 = (const float4*)(&f_lds[cl][0]);
#pragma unroll
      for (int sb = 0; sb < 128; sb += 8) {
        float4 ua = u4[sb / 4], ub = u4[sb / 4 + 1];
        int wb = (li * 8 + 120 - sb) >> 2;
        float4 w0 = f4[wb], w1 = f4[wb + 1], w2 = f4[wb + 2], w3 = f4[wb + 3];
        float u8[8] = {ua.x, ua.y, ua.z, ua.w, ub.x, ub.y, ub.z, ub.w};
        float wv[16] = {w0.x, w0.y, w0.z, w0.w, w1.x, w1.y, w1.z, w1.w,
                        w2.x, w2.y, w2.z, w2.w, w3.x, w3.y, w3.z, w3.w};
#pragma unroll
        for (int m = 0; m < 8; ++m)
#pragma unroll
          for (int j = 0; j < 8; ++j)
            acc[j] = fmaf(u8[m], wv[j + 7 - m], acc[j]);
      }
      __syncthreads();
    }
    float* op = o + (size_t)(cbase + cl) * L_SEQ + lt * 128 + li * 8;
    float4 o0 = {acc[0], acc[1], acc[2], acc[3]};
    float4 o1 = {acc[4], acc[5], acc[6], acc[7]};
    *(float4*)op = o0;
    *(float4*)(op + 4) = o1;
  }
}

// ---------------- gates: g[h,l] = relu(v_f^T M k_f + b)^2 + eps,  M[d][e]=wgz[d*64+e]*kv[d*64+e] ----------------
__global__ __launch_bounds__(256) void gate_kernel(const float* __restrict__ kf, const float* __restrict__ vf,
    const float* __restrict__ wgz_w, const float* __restrict__ wgz_b, const float* __restrict__ kvs,
    float* __restrict__ g)
{
  __shared__ float MT[64][68];
  __shared__ float kb[64][68];
  __shared__ float vb[64][68];
  __shared__ float yb[64][68];
  __shared__ float part[4][64];
  int h = blockIdx.y, l0 = blockIdx.x * 64;
  int tid = threadIdx.x;
#pragma unroll
  for (int k = 0; k < 16; ++k) {
    int idx = tid + k * 256;
    int a = idx >> 6, b = idx & 63;
    MT[b][a] = wgz_w[idx] * kvs[idx];  // MT[e][d] = M[d][e]
    kb[a][b] = kf[(size_t)(h * 64 + a) * L_SEQ + l0 + b];
    vb[a][b] = vf[(size_t)(h * 64 + a) * L_SEQ + l0 + b];
  }
  __syncthreads();
  // y[d][l] = sum_e M[d][e]*k[e][l]
  int lg = tid & 15, dg = tid >> 4;
  float acc[4][4] = {};
  for (int e = 0; e < 64; ++e) {
    float4 mv4 = *(const float4*)(&MT[e][dg * 4]);
    float4 kv4 = *(const float4*)(&kb[e][lg * 4]);
    float mvv[4] = {mv4.x, mv4.y, mv4.z, mv4.w};
    float kvv[4] = {kv4.x, kv4.y, kv4.z, kv4.w};
#pragma unroll
    for (int r = 0; r < 4; ++r)
#pragma unroll
      for (int j = 0; j < 4; ++j)
        acc[r][j] = fmaf(mvv[r], kvv[j], acc[r][j]);
  }
#pragma unroll
  for (int r = 0; r < 4; ++r)
#pragma unroll
    for (int j = 0; j < 4; ++j)
      yb[dg * 4 + r][lg * 4 + j] = acc[r][j];
  __syncthreads();
  int l = tid & 63, p = tid >> 6;
  float s = 0.f;
#pragma unroll
  for (int dd = 0; dd < 16; ++dd) {
    int d = p * 16 + dd;
    s = fmaf(yb[d][l], vb[d][l], s);
  }
  part[p][l] = s;
  __syncthreads();
  if (tid < 64) {
    float logit = part[0][tid] + part[1][tid] + part[2][tid] + part[3][tid] + wgz_b[0];
    float rl = fmaxf(logit, 0.f);
    g[h * L_SEQ + l0 + tid] = rl * rl + EPSF;
  }
}

// ---------------- per-chunk partial states: A_c[h,ch][d][e] = sum_t g*v_f[d,t]*k_f[e,t] (chunk=64) ----------------
__global__ __launch_bounds__(256) void partials_kernel(const float* __restrict__ kf, const float* __restrict__ vf,
    const float* __restrict__ g, float* __restrict__ A, float* __restrict__ gsum)
{
  __shared__ float kb[64][66];
  __shared__ float vb[64][66];
  __shared__ float gl[64];
  int h = blockIdx.y, ch = blockIdx.x;
  int t0 = ch * 64, tid = threadIdx.x;
#pragma unroll
  for (int k = 0; k < 16; ++k) {
    int idx = tid + k * 256;
    int c = idx >> 6, t = idx & 63;
    kb[c][t] = kf[(size_t)(h * 64 + c) * L_SEQ + t0 + t];
    vb[c][t] = vf[(size_t)(h * 64 + c) * L_SEQ + t0 + t];
  }
  if (tid < 64) gl[tid] = g[h * L_SEQ + t0 + tid];
  __syncthreads();
  int eg = tid & 15, dg = tid >> 4;
  float acc[4][4] = {};
  for (int t = 0; t < 64; ++t) {
    float gt = gl[t];
    float kv4[4], vv4[4];
#pragma unroll
    for (int j = 0; j < 4; ++j) kv4[j] = kb[eg * 4 + j][t] * gt;
#pragma unroll
    for (int r = 0; r < 4; ++r) vv4[r] = vb[dg * 4 + r][t];
#pragma unroll
    for (int r = 0; r < 4; ++r)
#pragma unroll
      for (int j = 0; j < 4; ++j)
        acc[r][j] = fmaf(vv4[r], kv4[j], acc[r][j]);
  }
  float* Ap = A + ((size_t)(h * 32 + ch)) * 4096;
#pragma unroll
  for (int r = 0; r < 4; ++r)
#pragma unroll
    for (int j = 0; j < 4; ++j)
      Ap[(dg * 4 + r) * 64 + eg * 4 + j] = acc[r][j];
  if (tid == 0) {
    float s = 0.f;
    for (int t = 0; t < 64; ++t) s += gl[t];
    gsum[h * 32 + ch] = s;
  }
}

// ---------------- exclusive prefix over 32 chunks ----------------
__global__ void prefix_kernel(const float* __restrict__ A, const float* __restrict__ gsum,
    float* __restrict__ Sprev, float* __restrict__ Gprev)
{
  int flat = blockIdx.x * 256 + threadIdx.x;  // 0..32767
  int h = flat >> 12, de = flat & 4095;
  float run = 0.f;
  for (int c = 0; c < 32; ++c) {
    size_t idx = ((size_t)(h * 32 + c)) * 4096 + de;
    Sprev[idx] = run;
    run += A[idx];
  }
  if (flat < 8) {
    float r = 0.f;
    for (int c = 0; c < 32; ++c) { Gprev[flat * 32 + c] = r; r += gsum[flat * 32 + c]; }
  }
}

// ---------------- attention: carry (q@Sprev) + in-chunk gated quadratic, /G, l2norm, write sp [L,512] ----------------
__global__ __launch_bounds__(256) void attn_kernel(const float* __restrict__ q, const float* __restrict__ kf,
    const float* __restrict__ vf, const float* __restrict__ g, const float* __restrict__ Sprev,
    const float* __restrict__ Gprev, float* __restrict__ sp)
{
  __shared__ float qT[64][68];  // [d][l]
  __shared__ float SW[64][69];  // Sprev[d][e], reused as w[l][t]
  __shared__ float vb[64][68];  // [d][t]
  __shared__ float kb[64][69];  // [e][t]
  __shared__ float gl[64], Gs[64], rsq[64];
  int h = blockIdx.y, ch = blockIdx.x;
  int t0 = ch * 64, tid = threadIdx.x;
  const float* Sp = Sprev + ((size_t)(h * 32 + ch)) * 4096;
#pragma unroll
  for (int k = 0; k < 16; ++k) {
    int idx = tid + k * 256;
    int a = idx >> 6, b = idx & 63;
    qT[b][a] = q[(size_t)(t0 + a) * D_MODEL + h * 64 + b];  // a=l, b=d
    SW[a][b] = Sp[idx];                                     // a=d, b=e
    vb[a][b] = vf[(size_t)(h * 64 + a) * L_SEQ + t0 + b];
    kb[a][b] = kf[(size_t)(h * 64 + a) * L_SEQ + t0 + b];
  }
  if (tid < 64) { gl[tid] = g[h * L_SEQ + t0 + tid]; rsq[tid] = 0.f; }
  __syncthreads();
  // inclusive scan of gates (wave 0)
  if (tid < 64) {
    float val = gl[tid];
#pragma unroll
    for (int off = 1; off < 64; off <<= 1) {
      float o = __shfl_up(val, (unsigned)off, 64);
      if (tid >= off) val += o;
    }
    Gs[tid] = fmaxf(Gprev[h * 32 + ch] + val, EPSF);
  }
  int lg = tid & 15, eg = tid >> 4;
  float acc[4][4] = {};
  // Phase A: carry = q @ Sprev
  for (int d = 0; d < 64; ++d) {
    float4 q4 = *(const float4*)(&qT[d][lg * 4]);
    float qv[4] = {q4.x, q4.y, q4.z, q4.w};
    float sv[4];
#pragma unroll
    for (int j = 0; j < 4; ++j) sv[j] = SW[d][eg * 4 + j];
#pragma unroll
    for (int r = 0; r < 4; ++r)
#pragma unroll
      for (int j = 0; j < 4; ++j)
        acc[r][j] = fmaf(qv[r], sv[j], acc[r][j]);
  }
  __syncthreads();
  // Phase B: scores[l][t] = q[l].v_f[t]; w = mask*g[t]*score  (overwrites SW)
  float sc[4][4] = {};
  for (int d = 0; d < 64; ++d) {
    float4 q4 = *(const float4*)(&qT[d][lg * 4]);
    float4 v4 = *(const float4*)(&vb[d][eg * 4]);
    float qv[4] = {q4.x, q4.y, q4.z, q4.w};
    float vv[4] = {v4.x, v4.y, v4.z, v4.w};
#pragma unroll
    for (int r = 0; r < 4; ++r)
#pragma unroll
      for (int m = 0; m < 4; ++m)
        sc[r][m] = fmaf(qv[r], vv[m], sc[r][m]);
  }
#pragma unroll
  for (int r = 0; r < 4; ++r)
#pragma unroll
    for (int m = 0; m < 4; ++m) {
      int ll = lg * 4 + r, tt = eg * 4 + m;
      SW[ll][tt] = (tt <= ll) ? sc[r][m] * gl[tt] : 0.f;
    }
  __syncthreads();
  // Phase C: acc += w @ k_f^T
  for (int t = 0; t < 64; ++t) {
    float wv4[4], kv4[4];
#pragma unroll
    for (int r = 0; r < 4; ++r) wv4[r] = SW[lg * 4 + r][t];
#pragma unroll
    for (int j = 0; j < 4; ++j) kv4[j] = kb[eg * 4 + j][t];
#pragma unroll
    for (int r = 0; r < 4; ++r)
#pragma unroll
      for (int j = 0; j < 4; ++j)
        acc[r][j] = fmaf(wv4[r], kv4[j], acc[r][j]);
  }
  // epilogue: /G, l2norm over e, store
  float val[4][4];
#pragma unroll
  for (int r = 0; r < 4; ++r) {
    float gi = 1.f / Gs[lg * 4 + r];
    float pr = 0.f;
#pragma unroll
    for (int j = 0; j < 4; ++j) { float v = acc[r][j] * gi; val[r][j] = v; pr = fmaf(v, v, pr); }
    atomicAdd(&rsq[lg * 4 + r], pr);
  }
  __syncthreads();
#pragma unroll
  for (int r = 0; r < 4; ++r) {
    float inv = 1.f / fmaxf(sqrtf(rsq[lg * 4 + r]), EPSF);
#pragma unroll
    for (int j = 0; j < 4; ++j)
      sp[(size_t)(t0 + lg * 4 + r) * D_MODEL + h * 64 + eg * 4 + j] = val[r][j] * inv;
  }
}

extern "C" void kernel_launch(void* const* d_in, const int* in_sizes, int n_in,
                              void* d_out, int out_size, void* d_ws, size_t ws_size,
                              hipStream_t stream) {
  const float* x = (const float*)d_in[0];
  const float* sb = (const float*)d_in[1];
  const float* wq_w = (const float*)d_in[2];
  const float* wq_b = (const float*)d_in[3];
  const float* wk_w = (const float*)d_in[4];
  const float* wk_b = (const float*)d_in[5];
  const float* wv_w = (const float*)d_in[6];
  const float* wv_b = (const float*)d_in[7];
  const float* wo_w = (const float*)d_in[8];
  const float* wo_b = (const float*)d_in[9];
  const float* td_w = (const float*)d_in[10];
  const float* td_b = (const float*)d_in[11];
  const float* wgz_w = (const float*)d_in[12];
  const float* wgz_b = (const float*)d_in[13];
  const float* kvs = (const float*)d_in[14];
  // d_in[15] (qk_norm_scale) unused — matches reference.
  float* out = (float*)d_out;

  char* ws = (char*)d_ws;
  size_t off = 0;
  auto alloc = [&](size_t bytes) -> void* {
    void* p = ws + off;
    off += (bytes + 255) & ~(size_t)255;
    return p;
  };
  __hip_bfloat16* xb  = (__hip_bfloat16*)alloc((size_t)L_SEQ * D_MODEL * 2);
  __hip_bfloat16* sbb = (__hip_bfloat16*)alloc((size_t)L_SEQ * D_MODEL * 2);
  __hip_bfloat16* wqb = (__hip_bfloat16*)alloc((size_t)D_MODEL * D_MODEL * 2);
  __hip_bfloat16* wkb = (__hip_bfloat16*)alloc((size_t)D_MODEL * D_MODEL * 2);
  __hip_bfloat16* wvb = (__hip_bfloat16*)alloc((size_t)D_MODEL * D_MODEL * 2);
  __hip_bfloat16* tdb = (__hip_bfloat16*)alloc((size_t)D_MODEL * D_MODEL * 2);
  __hip_bfloat16* wob = (__hip_bfloat16*)alloc((size_t)D_MODEL * D_MODEL * 2);
  __hip_bfloat16* spb = (__hip_bfloat16*)alloc((size_t)L_SEQ * D_MODEL * 2);
  float* qbuf  = (float*)alloc((size_t)L_SEQ * D_MODEL * 4);
  float* kT    = (float*)alloc((size_t)D_MODEL * L_SEQ * 4);
  float* vT    = (float*)alloc((size_t)D_MODEL * L_SEQ * 4);
  float* fT    = (float*)alloc((size_t)D_MODEL * L_SEQ * 4);
  float* kfT   = (float*)alloc((size_t)D_MODEL * L_SEQ * 4);
  float* vfT   = (float*)alloc((size_t)D_MODEL * L_SEQ * 4);
  float* gbuf  = (float*)alloc((size_t)NH * L_SEQ * 4);
  float* gsum  = (float*)alloc((size_t)NH * 32 * 4);
  float* Abuf  = (float*)alloc((size_t)NH * 32 * 4096 * 4);
  float* Sprev = (float*)alloc((size_t)NH * 32 * 4096 * 4);
  float* Gprev = (float*)alloc((size_t)NH * 32 * 4);
  float* spbuf = (float*)alloc((size_t)L_SEQ * D_MODEL * 4);

  cvt_bf16_kernel<<<512, 256, 0, stream>>>(x, xb, L_SEQ * D_MODEL);
  cvt_bf16_kernel<<<512, 256, 0, stream>>>(sb, sbb, L_SEQ * D_MODEL);
  cvt_bf16_kernel<<<256, 256, 0, stream>>>(wq_w, wqb, D_MODEL * D_MODEL);
  cvt_bf16_kernel<<<256, 256, 0, stream>>>(wk_w, wkb, D_MODEL * D_MODEL);
  cvt_bf16_kernel<<<256, 256, 0, stream>>>(wv_w, wvb, D_MODEL * D_MODEL);
  cvt_bf16_kernel<<<256, 256, 0, stream>>>(td_w, tdb, D_MODEL * D_MODEL);
  cvt_bf16_kernel<<<256, 256, 0, stream>>>(wo_w, wob, D_MODEL * D_MODEL);

  dim3 gg(L_SEQ / 64, D_MODEL / 64);
  gemm_bt_kernel<0><<<gg, 256, 0, stream>>>(xb, wqb, wq_b, qbuf, L_SEQ, D_MODEL, D_MODEL);
  gemm_bt_kernel<1><<<gg, 256, 0, stream>>>(xb, wkb, wk_b, kT, L_SEQ, D_MODEL, D_MODEL);
  gemm_bt_kernel<1><<<gg, 256, 0, stream>>>(xb, wvb, wv_b, vT, L_SEQ, D_MODEL, D_MODEL);
  gemm_bt_kernel<1><<<gg, 256, 0, stream>>>(sbb, tdb, td_b, fT, L_SEQ, D_MODEL, D_MODEL);

  l2norm_kernel<<<dim3(8, 8, 2), 256, 0, stream>>>(kT, vT);
  conv_kernel<<<dim3(32, 8, 2), 256, 0, stream>>>(kT, vT, fT, kfT, vfT);
  gate_kernel<<<dim3(32, 8), 256, 0, stream>>>(kfT, vfT, wgz_w, wgz_b, kvs, gbuf);
  partials_kernel<<<dim3(32, 8), 256, 0, stream>>>(kfT, vfT, gbuf, Abuf, gsum);
  prefix_kernel<<<128, 256, 0, stream>>>(Abuf, gsum, Sprev, Gprev);
  attn_kernel<<<dim3(32, 8), 256, 0, stream>>>(qbuf, kfT, vfT, gbuf, Sprev, Gprev, spbuf);

  cvt_bf16_kernel<<<512, 256, 0, stream>>>(spbuf, spb, L_SEQ * D_MODEL);
  gemm_bt_kernel<0><<<gg, 256, 0, stream>>>(spb, wob, wo_b, out, L_SEQ, D_MODEL, D_MODEL);
}

// Round 2
// 337.879 us; speedup vs baseline: 1.1993x; 1.1993x over previous
//
#include <hip/hip_runtime.h>
#include <hip/hip_bf16.h>

#define L_SEQ 2048
#define D_MODEL 512
#define NH 8
#define HD 64
#define EPSF 1e-5f

typedef __attribute__((ext_vector_type(8))) short short8;
typedef __attribute__((ext_vector_type(4))) float f32x4;

// ---------------- prep: fp32->bf16 for 7 tensors + zero conv output buffers ----------------
__global__ __launch_bounds__(256) void prep_kernel(const float* __restrict__ x,
    const float* __restrict__ sb, const float* __restrict__ wq, const float* __restrict__ wk,
    const float* __restrict__ wv, const float* __restrict__ td, const float* __restrict__ wo,
    __hip_bfloat16* __restrict__ xb, __hip_bfloat16* __restrict__ sbb,
    __hip_bfloat16* __restrict__ wqb, __hip_bfloat16* __restrict__ wkb,
    __hip_bfloat16* __restrict__ wvb, __hip_bfloat16* __restrict__ tdb,
    __hip_bfloat16* __restrict__ wob, float4* __restrict__ zbase)
{
  int i = blockIdx.x * 256 + threadIdx.x;
  if (i < 2097152) {
    if (i < 1048576) xb[i] = __float2bfloat16(x[i]);
    else sbb[i - 1048576] = __float2bfloat16(sb[i - 1048576]);
  } else if (i < 3407872) {
    int j = i - 2097152;
    int w = j >> 18;
    int r = j & 262143;
    const float* s = (w == 0) ? wq : (w == 1) ? wk : (w == 2) ? wv : (w == 3) ? td : wo;
    __hip_bfloat16* d = (w == 0) ? wqb : (w == 1) ? wkb : (w == 2) ? wvb : (w == 3) ? tdb : wob;
    d[r] = __float2bfloat16(s[r]);
  } else if (i < 3932160) {
    zbase[i - 3407872] = float4{0.f, 0.f, 0.f, 0.f};
  }
}

// ---------------- batched GEMM: q,k,v,filters in one launch; l2norm fused for k,v ----------------
// O = A @ W^T + bias. z=0: q (untransposed [L,D]); z=1: kT (+norm); z=2: vT (+norm); z=3: fT.
// MFMA 16x16x32 bf16; C/D: col(n)=lane&15, row(m)=quad*4+r.
__global__ __launch_bounds__(256) void gemm4_kernel(
    const __hip_bfloat16* __restrict__ xb, const __hip_bfloat16* __restrict__ sbb,
    const __hip_bfloat16* __restrict__ wqb, const __hip_bfloat16* __restrict__ wkb,
    const __hip_bfloat16* __restrict__ wvb, const __hip_bfloat16* __restrict__ tdb,
    const float* __restrict__ bq, const float* __restrict__ bk,
    const float* __restrict__ bv, const float* __restrict__ btd,
    float* __restrict__ qout, float* __restrict__ kT, float* __restrict__ vT,
    float* __restrict__ fT)
{
  int z = blockIdx.z;
  const __hip_bfloat16* A = (z == 3) ? sbb : xb;
  const __hip_bfloat16* W = (z == 0) ? wqb : (z == 1) ? wkb : (z == 2) ? wvb : tdb;
  const float* bias = (z == 0) ? bq : (z == 1) ? bk : (z == 2) ? bv : btd;
  float* O = (z == 0) ? qout : (z == 1) ? kT : (z == 2) ? vT : fT;
  const int M = L_SEQ, N = D_MODEL, K = D_MODEL;
  int lane = threadIdx.x & 63;
  int wave = threadIdx.x >> 6;
  int m0 = blockIdx.x * 64 + wave * 16;
  int n0 = blockIdx.y * 64;
  int lrow = lane & 15, quad = lane >> 4;
  const __hip_bfloat16* Ap = A + (size_t)(m0 + lrow) * K + quad * 8;
  const __hip_bfloat16* Wp = W + (size_t)(n0 + lrow) * K + quad * 8;
  f32x4 acc[4] = {};
  for (int k0 = 0; k0 < K; k0 += 32) {
    short8 a = *(const short8*)(Ap + k0);
#pragma unroll
    for (int j = 0; j < 4; ++j) {
      short8 b = *(const short8*)(Wp + k0 + (size_t)j * 16 * K);
      acc[j] = __builtin_amdgcn_mfma_f32_16x16x32_bf16(a, b, acc[j], 0, 0, 0);
    }
  }
  float bw[4];
#pragma unroll
  for (int j = 0; j < 4; ++j) bw[j] = bias[n0 + j * 16 + lrow];
  if (z == 0) {
#pragma unroll
    for (int j = 0; j < 4; ++j)
#pragma unroll
      for (int r = 0; r < 4; ++r)
        O[(size_t)(m0 + quad * 4 + r) * N + n0 + j * 16 + lrow] = acc[j][r] + bw[j];
  } else {
    float val[4][4];
#pragma unroll
    for (int j = 0; j < 4; ++j)
#pragma unroll
      for (int r = 0; r < 4; ++r) val[j][r] = acc[j][r] + bw[j];
    if (z == 1 || z == 2) {
      // l2-normalize over the head dim: this block's 64 n-columns are exactly one head.
      float pr[4];
#pragma unroll
      for (int r = 0; r < 4; ++r)
        pr[r] = val[0][r] * val[0][r] + val[1][r] * val[1][r] +
                val[2][r] * val[2][r] + val[3][r] * val[3][r];
#pragma unroll
      for (int off = 1; off < 16; off <<= 1)
#pragma unroll
        for (int r = 0; r < 4; ++r)
          pr[r] += __shfl_xor(pr[r], off, 64);
#pragma unroll
      for (int r = 0; r < 4; ++r) {
        float inv = 1.f / fmaxf(sqrtf(pr[r]), EPSF);
#pragma unroll
        for (int j = 0; j < 4; ++j) val[j][r] *= inv;
      }
    }
#pragma unroll
    for (int j = 0; j < 4; ++j) {
      float4 ov = {val[j][0], val[j][1], val[j][2], val[j][3]};
      *(float4*)(O + (size_t)(n0 + j * 16 + lrow) * M + m0 + quad * 4) = ov;
    }
  }
}

// ---------------- causal conv along L: out[c,l] += sum_{s<=l} F[c,l-s]*u[c,s] ----------------
// channel-major [512][2048]. 8 ch/block, 16 lanes/ch, 16 outputs/lane (l-tile 256), src chunks 128.
// grid: (64 chblk, 4 lt-pairs, 4 = tensor*2+split). Outputs combined via atomicAdd (buffers pre-zeroed).
// f_lds XOR swizzle phi(q)=q^((q>>3)&7) at float4-chunk granularity -> conflict-free reads.
__global__ __launch_bounds__(128) void conv_kernel(const float* __restrict__ uK,
    const float* __restrict__ uV, const float* __restrict__ F,
    float* __restrict__ oK, float* __restrict__ oV)
{
  __shared__ __align__(16) float f_lds[8 * 384];
  __shared__ __align__(16) float u_lds[8 * 132];
  int tensor = blockIdx.z >> 1;
  int split = blockIdx.z & 1;
  const float* u = tensor ? uV : uK;
  float* o = tensor ? oV : oK;
  int cbase = blockIdx.x * 8;
  int lt = blockIdx.y;          // paired with 7-lt; 18 src-chunk entries total, this block does 9
  int tid = threadIdx.x;
  int cl = tid >> 4, li = tid & 15;
  int n1 = 2 * lt + 2;
  float acc[16];
#pragma unroll
  for (int j = 0; j < 16; ++j) acc[j] = 0.f;
  int curP0 = -1;
  for (int e = split * 9; e < split * 9 + 9; ++e) {
    int P0, s0;
    if (e < n1) { P0 = lt * 256; s0 = e * 128; }
    else { P0 = (7 - lt) * 256; s0 = (e - n1) * 128; }
    if (P0 != curP0) {
      if (curP0 >= 0) {
        float* op = o + (size_t)(cbase + cl) * L_SEQ + curP0 + li * 16;
#pragma unroll
        for (int j = 0; j < 16; ++j) { atomicAdd(op + j, acc[j]); acc[j] = 0.f; }
      }
      curP0 = P0;
    }
    int W0 = P0 - s0 - 127;
    // stage u: 8 rows x 128 words
#pragma unroll
    for (int k = 0; k < 2; ++k) {
      int idx = tid + k * 128;
      int row = idx >> 5, qq = idx & 31;
      float4 t = *(const float4*)(u + (size_t)(cbase + row) * L_SEQ + s0 + 4 * qq);
      *(float4*)(&u_lds[row * 132 + 4 * qq]) = t;
    }
    // stage f: 8 rows x 96 chunks, swizzled, zero-padded outside [0,L)
#pragma unroll
    for (int k = 0; k < 6; ++k) {
      int idx = tid + k * 128;
      int row = idx / 96, q = idx - row * 96;
      const float* Fg = F + (size_t)(cbase + row) * L_SEQ;
      int g0 = W0 + 4 * q;
      float4 t;
      t.x = (g0 >= 0 && g0 < L_SEQ) ? Fg[g0] : 0.f;
      t.y = (g0 + 1 >= 0 && g0 + 1 < L_SEQ) ? Fg[g0 + 1] : 0.f;
      t.z = (g0 + 2 >= 0 && g0 + 2 < L_SEQ) ? Fg[g0 + 2] : 0.f;
      t.w = (g0 + 3 >= 0 && g0 + 3 < L_SEQ) ? Fg[g0 + 3] : 0.f;
      int ph = q ^ ((q >> 3) & 7);
      *(float4*)(&f_lds[row * 384 + 4 * ph]) = t;
    }
    __syncthreads();
    const float4* u4 = (const float4*)(&u_lds[cl * 132]);
    const float4* f4 = (const float4*)(&f_lds[cl * 384]);
#pragma unroll
    for (int sub = 0; sub < 8; ++sub) {
      float uu[16];
#pragma unroll
      for (int j = 0; j < 4; ++j) {
        float4 t = u4[sub * 4 + j];
        uu[4 * j] = t.x; uu[4 * j + 1] = t.y; uu[4 * j + 2] = t.z; uu[4 * j + 3] = t.w;
      }
      float fw[32];
      int q0 = 4 * li - 4 * sub + 28;
#pragma unroll
      for (int j = 0; j < 8; ++j) {
        int q = q0 + j;
        int ph = q ^ ((q >> 3) & 7);
        float4 t = f4[ph];
        fw[4 * j] = t.x; fw[4 * j + 1] = t.y; fw[4 * j + 2] = t.z; fw[4 * j + 3] = t.w;
      }
#pragma unroll
      for (int m = 0; m < 16; ++m)
#pragma unroll
        for (int oo = 0; oo < 16; ++oo)
          acc[oo] = fmaf(uu[m], fw[oo - m + 15], acc[oo]);
    }
    __syncthreads();
  }
  float* op = o + (size_t)(cbase + cl) * L_SEQ + curP0 + li * 16;
#pragma unroll
  for (int j = 0; j < 16; ++j) atomicAdd(op + j, acc[j]);
}

// ---------------- fused gate + partials per (h, chunk) ----------------
__global__ __launch_bounds__(256) void gatepart_kernel(const float* __restrict__ kf,
    const float* __restrict__ vf, const float* __restrict__ wgz_w,
    const float* __restrict__ wgz_b, const float* __restrict__ kvs,
    float* __restrict__ g, float* __restrict__ A, float* __restrict__ gsum)
{
  __shared__ float MT[64][68];
  __shared__ float kb[64][68];
  __shared__ float vb[64][68];
  __shared__ float yb[64][68];
  __shared__ float part[4][64];
  __shared__ float gl[64];
  int h = blockIdx.y, ch = blockIdx.x;
  int t0 = ch * 64, tid = threadIdx.x;
#pragma unroll
  for (int k = 0; k < 16; ++k) {
    int idx = tid + k * 256;
    int a = idx >> 6, b = idx & 63;
    MT[b][a] = wgz_w[idx] * kvs[idx];
    kb[a][b] = kf[(size_t)(h * 64 + a) * L_SEQ + t0 + b];
    vb[a][b] = vf[(size_t)(h * 64 + a) * L_SEQ + t0 + b];
  }
  __syncthreads();
  // y[d][l] = sum_e M[d][e]*k[e][l]
  int lg = tid & 15, dg = tid >> 4;
  {
    float acc[4][4] = {};
    for (int e = 0; e < 64; ++e) {
      float4 mv4 = *(const float4*)(&MT[e][dg * 4]);
      float4 kv4 = *(const float4*)(&kb[e][lg * 4]);
      float mvv[4] = {mv4.x, mv4.y, mv4.z, mv4.w};
      float kvv[4] = {kv4.x, kv4.y, kv4.z, kv4.w};
#pragma unroll
      for (int r = 0; r < 4; ++r)
#pragma unroll
        for (int j = 0; j < 4; ++j)
          acc[r][j] = fmaf(mvv[r], kvv[j], acc[r][j]);
    }
#pragma unroll
    for (int r = 0; r < 4; ++r)
#pragma unroll
      for (int j = 0; j < 4; ++j)
        yb[dg * 4 + r][lg * 4 + j] = acc[r][j];
  }
  __syncthreads();
  {
    int l = tid & 63, p = tid >> 6;
    float s = 0.f;
#pragma unroll
    for (int dd = 0; dd < 16; ++dd)
      s = fmaf(yb[p * 16 + dd][l], vb[p * 16 + dd][l], s);
    part[p][l] = s;
  }
  __syncthreads();
  if (tid < 64) {
    float logit = part[0][tid] + part[1][tid] + part[2][tid] + part[3][tid] + wgz_b[0];
    float rl = fmaxf(logit, 0.f);
    float gv = rl * rl + EPSF;
    g[h * L_SEQ + t0 + tid] = gv;
    gl[tid] = gv;
  }
  __syncthreads();
  // partials: A[d][e] = sum_t g[t]*v[d][t]*k[e][t]
  int eg = tid & 15, dg2 = tid >> 4;
  float acc[4][4] = {};
  for (int t = 0; t < 64; ++t) {
    float gt = gl[t];
    float kv4[4], vv4[4];
#pragma unroll
    for (int j = 0; j < 4; ++j) kv4[j] = kb[eg * 4 + j][t] * gt;
#pragma unroll
    for (int r = 0; r < 4; ++r) vv4[r] = vb[dg2 * 4 + r][t];
#pragma unroll
    for (int r = 0; r < 4; ++r)
#pragma unroll
      for (int j = 0; j < 4; ++j)
        acc[r][j] = fmaf(vv4[r], kv4[j], acc[r][j]);
  }
  float* Ap = A + ((size_t)(h * 32 + ch)) * 4096;
#pragma unroll
  for (int r = 0; r < 4; ++r)
#pragma unroll
    for (int j = 0; j < 4; ++j)
      Ap[(dg2 * 4 + r) * 64 + eg * 4 + j] = acc[r][j];
  if (tid == 0) {
    float s = 0.f;
    for (int t = 0; t < 64; ++t) s += gl[t];
    gsum[h * 32 + ch] = s;
  }
}

// ---------------- exclusive prefix over 32 chunks ----------------
__global__ void prefix_kernel(const float* __restrict__ A, const float* __restrict__ gsum,
    float* __restrict__ Sprev, float* __restrict__ Gprev)
{
  int flat = blockIdx.x * 256 + threadIdx.x;  // 0..32767
  int h = flat >> 12, de = flat & 4095;
  float run = 0.f;
  for (int c = 0; c < 32; ++c) {
    size_t idx = ((size_t)(h * 32 + c)) * 4096 + de;
    Sprev[idx] = run;
    run += A[idx];
  }
  if (flat < 8) {
    float r = 0.f;
    for (int c = 0; c < 32; ++c) { Gprev[flat * 32 + c] = r; r += gsum[flat * 32 + c]; }
  }
}

// ---------------- attention: carry + in-chunk gated quadratic, /G, l2norm, bf16 store ----------------
__global__ __launch_bounds__(256) void attn_kernel(const float* __restrict__ q,
    const float* __restrict__ kf, const float* __restrict__ vf, const float* __restrict__ g,
    const float* __restrict__ Sprev, const float* __restrict__ Gprev,
    __hip_bfloat16* __restrict__ sp)
{
  __shared__ float qT[64][68];
  __shared__ float SW[64][69];
  __shared__ float vb[64][68];
  __shared__ float kb[64][69];
  __shared__ float gl[64], Gs[64], rsq[64];
  int h = blockIdx.y, ch = blockIdx.x;
  int t0 = ch * 64, tid = threadIdx.x;
  const float* Sp = Sprev + ((size_t)(h * 32 + ch)) * 4096;
#pragma unroll
  for (int k = 0; k < 16; ++k) {
    int idx = tid + k * 256;
    int a = idx >> 6, b = idx & 63;
    qT[b][a] = q[(size_t)(t0 + a) * D_MODEL + h * 64 + b];
    SW[a][b] = Sp[idx];
    vb[a][b] = vf[(size_t)(h * 64 + a) * L_SEQ + t0 + b];
    kb[a][b] = kf[(size_t)(h * 64 + a) * L_SEQ + t0 + b];
  }
  if (tid < 64) { gl[tid] = g[h * L_SEQ + t0 + tid]; rsq[tid] = 0.f; }
  __syncthreads();
  if (tid < 64) {
    float val = gl[tid];
#pragma unroll
    for (int off = 1; off < 64; off <<= 1) {
      float o = __shfl_up(val, (unsigned)off, 64);
      if (tid >= off) val += o;
    }
    Gs[tid] = fmaxf(Gprev[h * 32 + ch] + val, EPSF);
  }
  int lg = tid & 15, eg = tid >> 4;
  float acc[4][4] = {};
  for (int d = 0; d < 64; ++d) {
    float4 q4 = *(const float4*)(&qT[d][lg * 4]);
    float qv[4] = {q4.x, q4.y, q4.z, q4.w};
    float sv[4];
#pragma unroll
    for (int j = 0; j < 4; ++j) sv[j] = SW[d][eg * 4 + j];
#pragma unroll
    for (int r = 0; r < 4; ++r)
#pragma unroll
      for (int j = 0; j < 4; ++j)
        acc[r][j] = fmaf(qv[r], sv[j], acc[r][j]);
  }
  __syncthreads();
  float sc[4][4] = {};
  for (int d = 0; d < 64; ++d) {
    float4 q4 = *(const float4*)(&qT[d][lg * 4]);
    float4 v4 = *(const float4*)(&vb[d][eg * 4]);
    float qv[4] = {q4.x, q4.y, q4.z, q4.w};
    float vv[4] = {v4.x, v4.y, v4.z, v4.w};
#pragma unroll
    for (int r = 0; r < 4; ++r)
#pragma unroll
      for (int m = 0; m < 4; ++m)
        sc[r][m] = fmaf(qv[r], vv[m], sc[r][m]);
  }
#pragma unroll
  for (int r = 0; r < 4; ++r)
#pragma unroll
    for (int m = 0; m < 4; ++m) {
      int ll = lg * 4 + r, tt = eg * 4 + m;
      SW[ll][tt] = (tt <= ll) ? sc[r][m] * gl[tt] : 0.f;
    }
  __syncthreads();
  for (int t = 0; t < 64; ++t) {
    float wv4[4], kv4[4];
#pragma unroll
    for (int r = 0; r < 4; ++r) wv4[r] = SW[lg * 4 + r][t];
#pragma unroll
    for (int j = 0; j < 4; ++j) kv4[j] = kb[eg * 4 + j][t];
#pragma unroll
    for (int r = 0; r < 4; ++r)
#pragma unroll
      for (int j = 0; j < 4; ++j)
        acc[r][j] = fmaf(wv4[r], kv4[j], acc[r][j]);
  }
  float val[4][4];
#pragma unroll
  for (int r = 0; r < 4; ++r) {
    float gi = 1.f / Gs[lg * 4 + r];
    float pr = 0.f;
#pragma unroll
    for (int j = 0; j < 4; ++j) { float v = acc[r][j] * gi; val[r][j] = v; pr = fmaf(v, v, pr); }
    atomicAdd(&rsq[lg * 4 + r], pr);
  }
  __syncthreads();
#pragma unroll
  for (int r = 0; r < 4; ++r) {
    float inv = 1.f / fmaxf(sqrtf(rsq[lg * 4 + r]), EPSF);
    union { ushort4 u; __hip_bfloat16 hh[4]; } pk;
#pragma unroll
    for (int j = 0; j < 4; ++j) pk.hh[j] = __float2bfloat16(val[r][j] * inv);
    *(ushort4*)(sp + (size_t)(t0 + lg * 4 + r) * D_MODEL + h * 64 + eg * 4) = pk.u;
  }
}

// ---------------- final GEMM: out = sp @ wo^T + b ----------------
__global__ __launch_bounds__(256) void gemm_out_kernel(const __hip_bfloat16* __restrict__ A,
    const __hip_bfloat16* __restrict__ W, const float* __restrict__ bias,
    float* __restrict__ O)
{
  const int N = D_MODEL, K = D_MODEL;
  int lane = threadIdx.x & 63;
  int wave = threadIdx.x >> 6;
  int m0 = blockIdx.x * 64 + wave * 16;
  int n0 = blockIdx.y * 64;
  int lrow = lane & 15, quad = lane >> 4;
  const __hip_bfloat16* Ap = A + (size_t)(m0 + lrow) * K + quad * 8;
  const __hip_bfloat16* Wp = W + (size_t)(n0 + lrow) * K + quad * 8;
  f32x4 acc[4] = {};
  for (int k0 = 0; k0 < K; k0 += 32) {
    short8 a = *(const short8*)(Ap + k0);
#pragma unroll
    for (int j = 0; j < 4; ++j) {
      short8 b = *(const short8*)(Wp + k0 + (size_t)j * 16 * K);
      acc[j] = __builtin_amdgcn_mfma_f32_16x16x32_bf16(a, b, acc[j], 0, 0, 0);
    }
  }
#pragma unroll
  for (int j = 0; j < 4; ++j) {
    int n = n0 + j * 16 + lrow;
    float bv = bias[n];
#pragma unroll
    for (int r = 0; r < 4; ++r)
      O[(size_t)(m0 + quad * 4 + r) * N + n] = acc[j][r] + bv;
  }
}

extern "C" void kernel_launch(void* const* d_in, const int* in_sizes, int n_in,
                              void* d_out, int out_size, void* d_ws, size_t ws_size,
                              hipStream_t stream) {
  const float* x = (const float*)d_in[0];
  const float* sb = (const float*)d_in[1];
  const float* wq_w = (const float*)d_in[2];
  const float* wq_b = (const float*)d_in[3];
  const float* wk_w = (const float*)d_in[4];
  const float* wk_b = (const float*)d_in[5];
  const float* wv_w = (const float*)d_in[6];
  const float* wv_b = (const float*)d_in[7];
  const float* wo_w = (const float*)d_in[8];
  const float* wo_b = (const float*)d_in[9];
  const float* td_w = (const float*)d_in[10];
  const float* td_b = (const float*)d_in[11];
  const float* wgz_w = (const float*)d_in[12];
  const float* wgz_b = (const float*)d_in[13];
  const float* kvs = (const float*)d_in[14];
  float* out = (float*)d_out;

  char* ws = (char*)d_ws;
  size_t off = 0;
  auto alloc = [&](size_t bytes) -> void* {
    void* p = ws + off;
    off += (bytes + 255) & ~(size_t)255;
    return p;
  };
  __hip_bfloat16* xb  = (__hip_bfloat16*)alloc((size_t)L_SEQ * D_MODEL * 2);
  __hip_bfloat16* sbb = (__hip_bfloat16*)alloc((size_t)L_SEQ * D_MODEL * 2);
  __hip_bfloat16* wqb = (__hip_bfloat16*)alloc((size_t)D_MODEL * D_MODEL * 2);
  __hip_bfloat16* wkb = (__hip_bfloat16*)alloc((size_t)D_MODEL * D_MODEL * 2);
  __hip_bfloat16* wvb = (__hip_bfloat16*)alloc((size_t)D_MODEL * D_MODEL * 2);
  __hip_bfloat16* tdb = (__hip_bfloat16*)alloc((size_t)D_MODEL * D_MODEL * 2);
  __hip_bfloat16* wob = (__hip_bfloat16*)alloc((size_t)D_MODEL * D_MODEL * 2);
  __hip_bfloat16* spb = (__hip_bfloat16*)alloc((size_t)L_SEQ * D_MODEL * 2);
  float* qbuf  = (float*)alloc((size_t)L_SEQ * D_MODEL * 4);
  float* kT    = (float*)alloc((size_t)D_MODEL * L_SEQ * 4);
  float* vT    = (float*)alloc((size_t)D_MODEL * L_SEQ * 4);
  float* fT    = (float*)alloc((size_t)D_MODEL * L_SEQ * 4);
  float* kfT   = (float*)alloc((size_t)D_MODEL * L_SEQ * 4);  // contiguous with vfT (zeroed in prep)
  float* vfT   = (float*)alloc((size_t)D_MODEL * L_SEQ * 4);
  float* gbuf  = (float*)alloc((size_t)NH * L_SEQ * 4);
  float* gsum  = (float*)alloc((size_t)NH * 32 * 4);
  float* Abuf  = (float*)alloc((size_t)NH * 32 * 4096 * 4);
  float* Sprev = (float*)alloc((size_t)NH * 32 * 4096 * 4);
  float* Gprev = (float*)alloc((size_t)NH * 32 * 4);

  prep_kernel<<<15360, 256, 0, stream>>>(x, sb, wq_w, wk_w, wv_w, td_w, wo_w,
                                         xb, sbb, wqb, wkb, wvb, tdb, wob, (float4*)kfT);
  gemm4_kernel<<<dim3(L_SEQ / 64, D_MODEL / 64, 4), 256, 0, stream>>>(
      xb, sbb, wqb, wkb, wvb, tdb, wq_b, wk_b, wv_b, td_b, qbuf, kT, vT, fT);
  conv_kernel<<<dim3(64, 4, 4), 128, 0, stream>>>(kT, vT, fT, kfT, vfT);
  gatepart_kernel<<<dim3(32, 8), 256, 0, stream>>>(kfT, vfT, wgz_w, wgz_b, kvs, gbuf, Abuf, gsum);
  prefix_kernel<<<128, 256, 0, stream>>>(Abuf, gsum, Sprev, Gprev);
  attn_kernel<<<dim3(32, 8), 256, 0, stream>>>(qbuf, kfT, vfT, gbuf, Sprev, Gprev, spb);
  gemm_out_kernel<<<dim3(L_SEQ / 64, D_MODEL / 64), 256, 0, stream>>>(spb, wob, wo_b, out);
}

// Round 3
// 261.201 us; speedup vs baseline: 1.5514x; 1.2936x over previous
//
#include <hip/hip_runtime.h>
#include <hip/hip_bf16.h>

#define L_SEQ 2048
#define D_MODEL 512
#define NH 8
#define HD 64
#define EPSF 1e-5f

// upad layout: [512 ch][2560], logical s at col 256+s; margins zeroed.
#define UPAD 2560
#define UOFF 256
// f4 layout: [512 ch][4 phase][2112]; f4[c][p][x] = F[c][2063 - x - p] (0 outside).
#define FCOPY 2112
#define FCH (4 * FCOPY)  // 8448

typedef __attribute__((ext_vector_type(8))) short short8;
typedef __attribute__((ext_vector_type(4))) short short4v;
typedef __attribute__((ext_vector_type(4))) float f32x4;

union bfu { ushort u; __hip_bfloat16 b; };

__device__ inline ushort bf_hi(float v, float& hv) {
  bfu t; t.b = __float2bfloat16(v); hv = __bfloat162float(t.b); return t.u;
}

// ---------------- prep: fp32->bf16 for 7 tensors + zero upad margins ----------------
__global__ __launch_bounds__(256) void prep_kernel(const float* __restrict__ x,
    const float* __restrict__ sb, const float* __restrict__ wq, const float* __restrict__ wk,
    const float* __restrict__ wv, const float* __restrict__ td, const float* __restrict__ wo,
    __hip_bfloat16* __restrict__ xb, __hip_bfloat16* __restrict__ sbb,
    __hip_bfloat16* __restrict__ wqb, __hip_bfloat16* __restrict__ wkb,
    __hip_bfloat16* __restrict__ wvb, __hip_bfloat16* __restrict__ tdb,
    __hip_bfloat16* __restrict__ wob,
    __hip_bfloat16* __restrict__ kuh, __hip_bfloat16* __restrict__ kul,
    __hip_bfloat16* __restrict__ vuh, __hip_bfloat16* __restrict__ vul)
{
  int i = blockIdx.x * 256 + threadIdx.x;
  if (i < 2097152) {
    if (i < 1048576) xb[i] = __float2bfloat16(x[i]);
    else sbb[i - 1048576] = __float2bfloat16(sb[i - 1048576]);
  } else if (i < 3407872) {
    int j = i - 2097152;
    int w = j >> 18;
    int r = j & 262143;
    const float* s = (w == 0) ? wq : (w == 1) ? wk : (w == 2) ? wv : (w == 3) ? td : wo;
    __hip_bfloat16* d = (w == 0) ? wqb : (w == 1) ? wkb : (w == 2) ? wvb : (w == 3) ? tdb : wob;
    d[r] = __float2bfloat16(s[r]);
  } else if (i < 3538944) {
    // zero upad margins: 4 arrays x 512 rows x 64 chunks of 8 elems (16B)
    int t = i - 3407872;
    int arr = t >> 15;
    int rem = t & 32767;
    int row = rem >> 6;
    int cc = rem & 63;
    int col = (cc < 32) ? cc * 8 : 2304 + (cc - 32) * 8;
    __hip_bfloat16* base = (arr == 0) ? kuh : (arr == 1) ? kul : (arr == 2) ? vuh : vul;
    *(int4*)(base + (size_t)row * UPAD + col) = int4{0, 0, 0, 0};
  }
}

// ---------------- batched GEMM: q,k,v,filters; l2norm + bf16 hi/lo pad-write for k,v ----------------
__global__ __launch_bounds__(256) void gemm4_kernel(
    const __hip_bfloat16* __restrict__ xb, const __hip_bfloat16* __restrict__ sbb,
    const __hip_bfloat16* __restrict__ wqb, const __hip_bfloat16* __restrict__ wkb,
    const __hip_bfloat16* __restrict__ wvb, const __hip_bfloat16* __restrict__ tdb,
    const float* __restrict__ bq, const float* __restrict__ bk,
    const float* __restrict__ bv, const float* __restrict__ btd,
    float* __restrict__ qout, float* __restrict__ fT,
    __hip_bfloat16* __restrict__ kuh, __hip_bfloat16* __restrict__ kul,
    __hip_bfloat16* __restrict__ vuh, __hip_bfloat16* __restrict__ vul)
{
  int z = blockIdx.z;
  const __hip_bfloat16* A = (z == 3) ? sbb : xb;
  const __hip_bfloat16* W = (z == 0) ? wqb : (z == 1) ? wkb : (z == 2) ? wvb : tdb;
  const float* bias = (z == 0) ? bq : (z == 1) ? bk : (z == 2) ? bv : btd;
  const int M = L_SEQ, N = D_MODEL, K = D_MODEL;
  int lane = threadIdx.x & 63;
  int wave = threadIdx.x >> 6;
  int m0 = blockIdx.x * 64 + wave * 16;
  int n0 = blockIdx.y * 64;
  int lrow = lane & 15, quad = lane >> 4;
  const __hip_bfloat16* Ap = A + (size_t)(m0 + lrow) * K + quad * 8;
  const __hip_bfloat16* Wp = W + (size_t)(n0 + lrow) * K + quad * 8;
  f32x4 acc[4] = {};
  for (int k0 = 0; k0 < K; k0 += 32) {
    short8 a = *(const short8*)(Ap + k0);
#pragma unroll
    for (int j = 0; j < 4; ++j) {
      short8 b = *(const short8*)(Wp + k0 + (size_t)j * 16 * K);
      acc[j] = __builtin_amdgcn_mfma_f32_16x16x32_bf16(a, b, acc[j], 0, 0, 0);
    }
  }
  float bw[4];
#pragma unroll
  for (int j = 0; j < 4; ++j) bw[j] = bias[n0 + j * 16 + lrow];
  if (z == 0) {
#pragma unroll
    for (int j = 0; j < 4; ++j)
#pragma unroll
      for (int r = 0; r < 4; ++r)
        qout[(size_t)(m0 + quad * 4 + r) * N + n0 + j * 16 + lrow] = acc[j][r] + bw[j];
  } else if (z == 3) {
#pragma unroll
    for (int j = 0; j < 4; ++j) {
      float4 ov = {acc[j][0] + bw[j], acc[j][1] + bw[j], acc[j][2] + bw[j], acc[j][3] + bw[j]};
      *(float4*)(fT + (size_t)(n0 + j * 16 + lrow) * M + m0 + quad * 4) = ov;
    }
  } else {
    float val[4][4];
#pragma unroll
    for (int j = 0; j < 4; ++j)
#pragma unroll
      for (int r = 0; r < 4; ++r) val[j][r] = acc[j][r] + bw[j];
    // l2-normalize over head dim (this block's 64 n-cols = one head)
    float pr[4];
#pragma unroll
    for (int r = 0; r < 4; ++r)
      pr[r] = val[0][r] * val[0][r] + val[1][r] * val[1][r] +
              val[2][r] * val[2][r] + val[3][r] * val[3][r];
#pragma unroll
    for (int off = 1; off < 16; off <<= 1)
#pragma unroll
      for (int r = 0; r < 4; ++r)
        pr[r] += __shfl_xor(pr[r], off, 64);
    __hip_bfloat16* uh = (z == 1) ? kuh : vuh;
    __hip_bfloat16* ul = (z == 1) ? kul : vul;
#pragma unroll
    for (int r = 0; r < 4; ++r) {
      float inv = 1.f / fmaxf(sqrtf(pr[r]), EPSF);
#pragma unroll
      for (int j = 0; j < 4; ++j) val[j][r] *= inv;
    }
#pragma unroll
    for (int j = 0; j < 4; ++j) {
      ushort4 ph, pl;
      float hv;
      ph.x = bf_hi(val[j][0], hv); { bfu t; t.b = __float2bfloat16(val[j][0] - hv); pl.x = t.u; }
      ph.y = bf_hi(val[j][1], hv); { bfu t; t.b = __float2bfloat16(val[j][1] - hv); pl.y = t.u; }
      ph.z = bf_hi(val[j][2], hv); { bfu t; t.b = __float2bfloat16(val[j][2] - hv); pl.z = t.u; }
      ph.w = bf_hi(val[j][3], hv); { bfu t; t.b = __float2bfloat16(val[j][3] - hv); pl.w = t.u; }
      size_t base = (size_t)(n0 + j * 16 + lrow) * UPAD + UOFF + m0 + quad * 4;
      *(ushort4*)(uh + base) = ph;
      *(ushort4*)(ul + base) = pl;
    }
  }
}

// ---------------- build 4-phase reversed filter copies (hi/lo bf16) ----------------
__global__ __launch_bounds__(256) void frev_kernel(const float* __restrict__ fT,
    __hip_bfloat16* __restrict__ f4h, __hip_bfloat16* __restrict__ f4l)
{
  int t = blockIdx.x * 256 + threadIdx.x;
  if (t >= 512 * 4 * (FCOPY / 8)) return;
  int xc = t % (FCOPY / 8);
  int rest = t / (FCOPY / 8);
  int p = rest & 3;
  int c = rest >> 2;
  int x0 = xc * 8;
  const float* F = fT + (size_t)c * L_SEQ;
  ushort h8[8], l8[8];
#pragma unroll
  for (int i = 0; i < 8; ++i) {
    int idx = 2063 - p - (x0 + i);
    float v = (idx >= 0 && idx < L_SEQ) ? F[idx] : 0.f;
    float hv;
    h8[i] = bf_hi(v, hv);
    bfu tl; tl.b = __float2bfloat16(v - hv); l8[i] = tl.u;
  }
  size_t off = (size_t)c * FCH + (size_t)p * FCOPY + x0;
  *(ushort4*)(f4h + off) = ushort4{h8[0], h8[1], h8[2], h8[3]};
  *(ushort4*)(f4h + off + 4) = ushort4{h8[4], h8[5], h8[6], h8[7]};
  *(ushort4*)(f4l + off) = ushort4{l8[0], l8[1], l8[2], l8[3]};
  *(ushort4*)(f4l + off + 4) = ushort4{l8[4], l8[5], l8[6], l8[7]};
}

// ---------------- causal conv via MFMA Toeplitz ----------------
// wave = (tensor, channel, pair); pair handles out-tiles l0 = 256*pair and 256*(7-pair).
// Per s0 step (stride 32): A[m][k] = F[d+m-k] (d = l0 - s0) from phase copies,
// B[k][n] = u[s0+k+16n]. D[m][n] -> l = l0 + m + 16n. 3 hi/lo product MFMAs/tile.
__device__ inline short8 ld_pair(const __hip_bfloat16* p) {
  short4v a = *(const short4v*)p;
  short4v b = *(const short4v*)(p + 4);
  return __builtin_shufflevector(a, b, 0, 1, 2, 3, 4, 5, 6, 7);
}

__global__ __launch_bounds__(256) void conv_kernel(
    const __hip_bfloat16* __restrict__ kuh, const __hip_bfloat16* __restrict__ kul,
    const __hip_bfloat16* __restrict__ vuh, const __hip_bfloat16* __restrict__ vul,
    const __hip_bfloat16* __restrict__ f4h, const __hip_bfloat16* __restrict__ f4l,
    float* __restrict__ oK, float* __restrict__ oV)
{
  int wave = threadIdx.x >> 6, lane = threadIdx.x & 63;
  int flat = blockIdx.x * 4 + wave;
  int tensor = flat >> 11;
  int c = (flat >> 2) & 511;
  int pair = flat & 3;
  int l0_lo = 256 * pair;
  int l0_hi = 1792 - l0_lo;
  const __hip_bfloat16* uh = tensor ? vuh : kuh;
  const __hip_bfloat16* ul = tensor ? vul : kul;
  float* o = tensor ? oV : oK;
  int mn = lane & 15, quad = lane >> 4;

  size_t eb = (size_t)c * UPAD + 8 * quad + 16 * mn;  // s0=-256 start (UOFF-256=0)
  const __hip_bfloat16* pbh = uh + eb;
  const __hip_bfloat16* pbl = ul + eb;

  int j0c = 2063 - mn;
  int p4 = j0c & 3;
  size_t abase = (size_t)c * FCH + (size_t)p4 * FCOPY + (j0c - p4) + 8 * quad;
  const __hip_bfloat16* pfh_hi = f4h + abase - (l0_hi + 256);
  const __hip_bfloat16* pfl_hi = f4l + abase - (l0_hi + 256);
  const __hip_bfloat16* pfh_lo = f4h + abase - (l0_lo + 256);
  const __hip_bfloat16* pfl_lo = f4l + abase - (l0_lo + 256);

  int steps_lo = l0_lo / 32 + 9;
  int steps_hi = l0_hi / 32 + 9;
  f32x4 acc_hi = {}, acc_lo = {};
#pragma unroll 2
  for (int i = 0; i < steps_lo; ++i) {
    short8 bh = *(const short8*)pbh;
    short8 bl = *(const short8*)pbl;
    short8 fhh = ld_pair(pfh_hi);
    short8 fhl = ld_pair(pfl_hi);
    short8 flh = ld_pair(pfh_lo);
    short8 fll = ld_pair(pfl_lo);
    pbh += 32; pbl += 32; pfh_hi += 32; pfl_hi += 32; pfh_lo += 32; pfl_lo += 32;
    acc_hi = __builtin_amdgcn_mfma_f32_16x16x32_bf16(fhh, bh, acc_hi, 0, 0, 0);
    acc_hi = __builtin_amdgcn_mfma_f32_16x16x32_bf16(fhh, bl, acc_hi, 0, 0, 0);
    acc_hi = __builtin_amdgcn_mfma_f32_16x16x32_bf16(fhl, bh, acc_hi, 0, 0, 0);
    acc_lo = __builtin_amdgcn_mfma_f32_16x16x32_bf16(flh, bh, acc_lo, 0, 0, 0);
    acc_lo = __builtin_amdgcn_mfma_f32_16x16x32_bf16(flh, bl, acc_lo, 0, 0, 0);
    acc_lo = __builtin_amdgcn_mfma_f32_16x16x32_bf16(fll, bh, acc_lo, 0, 0, 0);
  }
#pragma unroll 2
  for (int i = steps_lo; i < steps_hi; ++i) {
    short8 bh = *(const short8*)pbh;
    short8 bl = *(const short8*)pbl;
    short8 fhh = ld_pair(pfh_hi);
    short8 fhl = ld_pair(pfl_hi);
    pbh += 32; pbl += 32; pfh_hi += 32; pfl_hi += 32;
    acc_hi = __builtin_amdgcn_mfma_f32_16x16x32_bf16(fhh, bh, acc_hi, 0, 0, 0);
    acc_hi = __builtin_amdgcn_mfma_f32_16x16x32_bf16(fhh, bl, acc_hi, 0, 0, 0);
    acc_hi = __builtin_amdgcn_mfma_f32_16x16x32_bf16(fhl, bh, acc_hi, 0, 0, 0);
  }
  size_t ob = (size_t)c * L_SEQ + 16 * mn + 4 * quad;
  *(float4*)(o + ob + l0_hi) = float4{acc_hi[0], acc_hi[1], acc_hi[2], acc_hi[3]};
  *(float4*)(o + ob + l0_lo) = float4{acc_lo[0], acc_lo[1], acc_lo[2], acc_lo[3]};
}

// ---------------- fused gate + partials per (h, chunk) ----------------
__global__ __launch_bounds__(256) void gatepart_kernel(const float* __restrict__ kf,
    const float* __restrict__ vf, const float* __restrict__ wgz_w,
    const float* __restrict__ wgz_b, const float* __restrict__ kvs,
    float* __restrict__ g, float* __restrict__ A, float* __restrict__ gsum)
{
  __shared__ float MT[64][68];
  __shared__ float kb[64][68];
  __shared__ float vb[64][68];
  __shared__ float yb[64][68];
  __shared__ float part[4][64];
  __shared__ float gl[64];
  int h = blockIdx.y, ch = blockIdx.x;
  int t0 = ch * 64, tid = threadIdx.x;
#pragma unroll
  for (int k = 0; k < 16; ++k) {
    int idx = tid + k * 256;
    int a = idx >> 6, b = idx & 63;
    MT[b][a] = wgz_w[idx] * kvs[idx];
    kb[a][b] = kf[(size_t)(h * 64 + a) * L_SEQ + t0 + b];
    vb[a][b] = vf[(size_t)(h * 64 + a) * L_SEQ + t0 + b];
  }
  __syncthreads();
  int lg = tid & 15, dg = tid >> 4;
  {
    float acc[4][4] = {};
    for (int e = 0; e < 64; ++e) {
      float4 mv4 = *(const float4*)(&MT[e][dg * 4]);
      float4 kv4 = *(const float4*)(&kb[e][lg * 4]);
      float mvv[4] = {mv4.x, mv4.y, mv4.z, mv4.w};
      float kvv[4] = {kv4.x, kv4.y, kv4.z, kv4.w};
#pragma unroll
      for (int r = 0; r < 4; ++r)
#pragma unroll
        for (int j = 0; j < 4; ++j)
          acc[r][j] = fmaf(mvv[r], kvv[j], acc[r][j]);
    }
#pragma unroll
    for (int r = 0; r < 4; ++r)
#pragma unroll
      for (int j = 0; j < 4; ++j)
        yb[dg * 4 + r][lg * 4 + j] = acc[r][j];
  }
  __syncthreads();
  {
    int l = tid & 63, p = tid >> 6;
    float s = 0.f;
#pragma unroll
    for (int dd = 0; dd < 16; ++dd)
      s = fmaf(yb[p * 16 + dd][l], vb[p * 16 + dd][l], s);
    part[p][l] = s;
  }
  __syncthreads();
  if (tid < 64) {
    float logit = part[0][tid] + part[1][tid] + part[2][tid] + part[3][tid] + wgz_b[0];
    float rl = fmaxf(logit, 0.f);
    float gv = rl * rl + EPSF;
    g[h * L_SEQ + t0 + tid] = gv;
    gl[tid] = gv;
  }
  __syncthreads();
  int eg = tid & 15, dg2 = tid >> 4;
  float acc[4][4] = {};
  for (int t = 0; t < 64; ++t) {
    float gt = gl[t];
    float kv4[4], vv4[4];
#pragma unroll
    for (int j = 0; j < 4; ++j) kv4[j] = kb[eg * 4 + j][t] * gt;
#pragma unroll
    for (int r = 0; r < 4; ++r) vv4[r] = vb[dg2 * 4 + r][t];
#pragma unroll
    for (int r = 0; r < 4; ++r)
#pragma unroll
      for (int j = 0; j < 4; ++j)
        acc[r][j] = fmaf(vv4[r], kv4[j], acc[r][j]);
  }
  float* Ap = A + ((size_t)(h * 32 + ch)) * 4096;
#pragma unroll
  for (int r = 0; r < 4; ++r)
#pragma unroll
    for (int j = 0; j < 4; ++j)
      Ap[(dg2 * 4 + r) * 64 + eg * 4 + j] = acc[r][j];
  if (tid == 0) {
    float s = 0.f;
    for (int t = 0; t < 64; ++t) s += gl[t];
    gsum[h * 32 + ch] = s;
  }
}

// ---------------- exclusive prefix over 32 chunks (in place) ----------------
__global__ void prefix_kernel(float* __restrict__ A, float* __restrict__ gsum)
{
  int flat = blockIdx.x * 256 + threadIdx.x;
  int h = flat >> 12, de = flat & 4095;
  float run = 0.f;
  for (int c = 0; c < 32; ++c) {
    size_t idx = ((size_t)(h * 32 + c)) * 4096 + de;
    float t = A[idx];
    A[idx] = run;
    run += t;
  }
  if (flat < 8) {
    float r = 0.f;
    for (int c = 0; c < 32; ++c) { float t = gsum[flat * 32 + c]; gsum[flat * 32 + c] = r; r += t; }
  }
}

// ---------------- attention: carry + in-chunk gated quadratic, /G, l2norm, bf16 store ----------------
__global__ __launch_bounds__(256) void attn_kernel(const float* __restrict__ q,
    const float* __restrict__ kf, const float* __restrict__ vf, const float* __restrict__ g,
    const float* __restrict__ Sprev, const float* __restrict__ Gprev,
    __hip_bfloat16* __restrict__ sp)
{
  __shared__ float qT[64][68];
  __shared__ float SW[64][69];
  __shared__ float vb[64][68];
  __shared__ float kb[64][69];
  __shared__ float gl[64], Gs[64], rsq[64];
  int h = blockIdx.y, ch = blockIdx.x;
  int t0 = ch * 64, tid = threadIdx.x;
  const float* Sp = Sprev + ((size_t)(h * 32 + ch)) * 4096;
#pragma unroll
  for (int k = 0; k < 16; ++k) {
    int idx = tid + k * 256;
    int a = idx >> 6, b = idx & 63;
    qT[b][a] = q[(size_t)(t0 + a) * D_MODEL + h * 64 + b];
    SW[a][b] = Sp[idx];
    vb[a][b] = vf[(size_t)(h * 64 + a) * L_SEQ + t0 + b];
    kb[a][b] = kf[(size_t)(h * 64 + a) * L_SEQ + t0 + b];
  }
  if (tid < 64) { gl[tid] = g[h * L_SEQ + t0 + tid]; rsq[tid] = 0.f; }
  __syncthreads();
  if (tid < 64) {
    float val = gl[tid];
#pragma unroll
    for (int off = 1; off < 64; off <<= 1) {
      float o = __shfl_up(val, (unsigned)off, 64);
      if (tid >= off) val += o;
    }
    Gs[tid] = fmaxf(Gprev[h * 32 + ch] + val, EPSF);
  }
  int lg = tid & 15, eg = tid >> 4;
  float acc[4][4] = {};
  for (int d = 0; d < 64; ++d) {
    float4 q4 = *(const float4*)(&qT[d][lg * 4]);
    float qv[4] = {q4.x, q4.y, q4.z, q4.w};
    float sv[4];
#pragma unroll
    for (int j = 0; j < 4; ++j) sv[j] = SW[d][eg * 4 + j];
#pragma unroll
    for (int r = 0; r < 4; ++r)
#pragma unroll
      for (int j = 0; j < 4; ++j)
        acc[r][j] = fmaf(qv[r], sv[j], acc[r][j]);
  }
  __syncthreads();
  float sc[4][4] = {};
  for (int d = 0; d < 64; ++d) {
    float4 q4 = *(const float4*)(&qT[d][lg * 4]);
    float4 v4 = *(const float4*)(&vb[d][eg * 4]);
    float qv[4] = {q4.x, q4.y, q4.z, q4.w};
    float vv[4] = {v4.x, v4.y, v4.z, v4.w};
#pragma unroll
    for (int r = 0; r < 4; ++r)
#pragma unroll
      for (int m = 0; m < 4; ++m)
        sc[r][m] = fmaf(qv[r], vv[m], sc[r][m]);
  }
#pragma unroll
  for (int r = 0; r < 4; ++r)
#pragma unroll
    for (int m = 0; m < 4; ++m) {
      int ll = lg * 4 + r, tt = eg * 4 + m;
      SW[ll][tt] = (tt <= ll) ? sc[r][m] * gl[tt] : 0.f;
    }
  __syncthreads();
  for (int t = 0; t < 64; ++t) {
    float wv4[4], kv4[4];
#pragma unroll
    for (int r = 0; r < 4; ++r) wv4[r] = SW[lg * 4 + r][t];
#pragma unroll
    for (int j = 0; j < 4; ++j) kv4[j] = kb[eg * 4 + j][t];
#pragma unroll
    for (int r = 0; r < 4; ++r)
#pragma unroll
      for (int j = 0; j < 4; ++j)
        acc[r][j] = fmaf(wv4[r], kv4[j], acc[r][j]);
  }
  float val[4][4];
#pragma unroll
  for (int r = 0; r < 4; ++r) {
    float gi = 1.f / Gs[lg * 4 + r];
    float pr = 0.f;
#pragma unroll
    for (int j = 0; j < 4; ++j) { float v = acc[r][j] * gi; val[r][j] = v; pr = fmaf(v, v, pr); }
    atomicAdd(&rsq[lg * 4 + r], pr);
  }
  __syncthreads();
#pragma unroll
  for (int r = 0; r < 4; ++r) {
    float inv = 1.f / fmaxf(sqrtf(rsq[lg * 4 + r]), EPSF);
    union { ushort4 u; __hip_bfloat16 hh[4]; } pk;
#pragma unroll
    for (int j = 0; j < 4; ++j) pk.hh[j] = __float2bfloat16(val[r][j] * inv);
    *(ushort4*)(sp + (size_t)(t0 + lg * 4 + r) * D_MODEL + h * 64 + eg * 4) = pk.u;
  }
}

// ---------------- final GEMM: out = sp @ wo^T + b ----------------
__global__ __launch_bounds__(256) void gemm_out_kernel(const __hip_bfloat16* __restrict__ A,
    const __hip_bfloat16* __restrict__ W, const float* __restrict__ bias,
    float* __restrict__ O)
{
  const int N = D_MODEL, K = D_MODEL;
  int lane = threadIdx.x & 63;
  int wave = threadIdx.x >> 6;
  int m0 = blockIdx.x * 64 + wave * 16;
  int n0 = blockIdx.y * 64;
  int lrow = lane & 15, quad = lane >> 4;
  const __hip_bfloat16* Ap = A + (size_t)(m0 + lrow) * K + quad * 8;
  const __hip_bfloat16* Wp = W + (size_t)(n0 + lrow) * K + quad * 8;
  f32x4 acc[4] = {};
  for (int k0 = 0; k0 < K; k0 += 32) {
    short8 a = *(const short8*)(Ap + k0);
#pragma unroll
    for (int j = 0; j < 4; ++j) {
      short8 b = *(const short8*)(Wp + k0 + (size_t)j * 16 * K);
      acc[j] = __builtin_amdgcn_mfma_f32_16x16x32_bf16(a, b, acc[j], 0, 0, 0);
    }
  }
#pragma unroll
  for (int j = 0; j < 4; ++j) {
    int n = n0 + j * 16 + lrow;
    float bv = bias[n];
#pragma unroll
    for (int r = 0; r < 4; ++r)
      O[(size_t)(m0 + quad * 4 + r) * N + n] = acc[j][r] + bv;
  }
}

extern "C" void kernel_launch(void* const* d_in, const int* in_sizes, int n_in,
                              void* d_out, int out_size, void* d_ws, size_t ws_size,
                              hipStream_t stream) {
  const float* x = (const float*)d_in[0];
  const float* sb = (const float*)d_in[1];
  const float* wq_w = (const float*)d_in[2];
  const float* wq_b = (const float*)d_in[3];
  const float* wk_w = (const float*)d_in[4];
  const float* wk_b = (const float*)d_in[5];
  const float* wv_w = (const float*)d_in[6];
  const float* wv_b = (const float*)d_in[7];
  const float* wo_w = (const float*)d_in[8];
  const float* wo_b = (const float*)d_in[9];
  const float* td_w = (const float*)d_in[10];
  const float* td_b = (const float*)d_in[11];
  const float* wgz_w = (const float*)d_in[12];
  const float* wgz_b = (const float*)d_in[13];
  const float* kvs = (const float*)d_in[14];
  float* out = (float*)d_out;

  char* ws = (char*)d_ws;
  size_t off = 0;
  auto alloc = [&](size_t bytes) -> void* {
    void* p = ws + off;
    off += (bytes + 255) & ~(size_t)255;
    return p;
  };
  __hip_bfloat16* xb  = (__hip_bfloat16*)alloc((size_t)L_SEQ * D_MODEL * 2);
  __hip_bfloat16* sbb = (__hip_bfloat16*)alloc((size_t)L_SEQ * D_MODEL * 2);
  __hip_bfloat16* wqb = (__hip_bfloat16*)alloc((size_t)D_MODEL * D_MODEL * 2);
  __hip_bfloat16* wkb = (__hip_bfloat16*)alloc((size_t)D_MODEL * D_MODEL * 2);
  __hip_bfloat16* wvb = (__hip_bfloat16*)alloc((size_t)D_MODEL * D_MODEL * 2);
  __hip_bfloat16* tdb = (__hip_bfloat16*)alloc((size_t)D_MODEL * D_MODEL * 2);
  __hip_bfloat16* wob = (__hip_bfloat16*)alloc((size_t)D_MODEL * D_MODEL * 2);
  __hip_bfloat16* spb = (__hip_bfloat16*)alloc((size_t)L_SEQ * D_MODEL * 2);
  __hip_bfloat16* kuh = (__hip_bfloat16*)alloc((size_t)D_MODEL * UPAD * 2);
  __hip_bfloat16* kul = (__hip_bfloat16*)alloc((size_t)D_MODEL * UPAD * 2);
  __hip_bfloat16* vuh = (__hip_bfloat16*)alloc((size_t)D_MODEL * UPAD * 2);
  __hip_bfloat16* vul = (__hip_bfloat16*)alloc((size_t)D_MODEL * UPAD * 2);
  __hip_bfloat16* f4h = (__hip_bfloat16*)alloc((size_t)D_MODEL * FCH * 2);
  __hip_bfloat16* f4l = (__hip_bfloat16*)alloc((size_t)D_MODEL * FCH * 2);
  float* qbuf  = (float*)alloc((size_t)L_SEQ * D_MODEL * 4);
  float* fT    = (float*)alloc((size_t)D_MODEL * L_SEQ * 4);
  float* kfT   = (float*)alloc((size_t)D_MODEL * L_SEQ * 4);
  float* vfT   = (float*)alloc((size_t)D_MODEL * L_SEQ * 4);
  float* gbuf  = (float*)alloc((size_t)NH * L_SEQ * 4);
  float* gsum  = (float*)alloc((size_t)NH * 32 * 4);
  float* Abuf  = (float*)alloc((size_t)NH * 32 * 4096 * 4);

  prep_kernel<<<13824, 256, 0, stream>>>(x, sb, wq_w, wk_w, wv_w, td_w, wo_w,
                                         xb, sbb, wqb, wkb, wvb, tdb, wob,
                                         kuh, kul, vuh, vul);
  gemm4_kernel<<<dim3(L_SEQ / 64, D_MODEL / 64, 4), 256, 0, stream>>>(
      xb, sbb, wqb, wkb, wvb, tdb, wq_b, wk_b, wv_b, td_b, qbuf, fT,
      kuh, kul, vuh, vul);
  frev_kernel<<<(512 * 4 * (FCOPY / 8) + 255) / 256, 256, 0, stream>>>(fT, f4h, f4l);
  conv_kernel<<<1024, 256, 0, stream>>>(kuh, kul, vuh, vul, f4h, f4l, kfT, vfT);
  gatepart_kernel<<<dim3(32, 8), 256, 0, stream>>>(kfT, vfT, wgz_w, wgz_b, kvs, gbuf, Abuf, gsum);
  prefix_kernel<<<128, 256, 0, stream>>>(Abuf, gsum);
  attn_kernel<<<dim3(32, 8), 256, 0, stream>>>(qbuf, kfT, vfT, gbuf, Abuf, gsum, spb);
  gemm_out_kernel<<<dim3(L_SEQ / 64, D_MODEL / 64), 256, 0, stream>>>(spb, wob, wo_b, out);
}

// Round 4
// 194.713 us; speedup vs baseline: 2.0811x; 1.3415x over previous
//
#include <hip/hip_runtime.h>
#include <hip/hip_bf16.h>
#include <hip/hip_fp16.h>

#define L_SEQ 2048
#define D_MODEL 512
#define NH 8
#define HD 64
#define EPSF 1e-5f

// u f16 layout: [512 ch][2560], logical s at col 256+s; margins zeroed.
#define UPAD 2560
#define UOFF 256
// filter LDS: 8 phase copies, stride 2120 f16 (=1060 words, == 4 mod 32 -> 2-way-free banks)
#define XLEN 2112
#define XPAD 2120

typedef __attribute__((ext_vector_type(8))) short short8;
typedef __attribute__((ext_vector_type(8))) _Float16 half8;
typedef __attribute__((ext_vector_type(4))) _Float16 half4v;
typedef __attribute__((ext_vector_type(4))) float f32x4;

// ---------------- prep: fp32->bf16 for 7 tensors + zero u16 margins ----------------
__global__ __launch_bounds__(256) void prep_kernel(const float* __restrict__ x,
    const float* __restrict__ sb, const float* __restrict__ wq, const float* __restrict__ wk,
    const float* __restrict__ wv, const float* __restrict__ td, const float* __restrict__ wo,
    __hip_bfloat16* __restrict__ xb, __hip_bfloat16* __restrict__ sbb,
    __hip_bfloat16* __restrict__ wqb, __hip_bfloat16* __restrict__ wkb,
    __hip_bfloat16* __restrict__ wvb, __hip_bfloat16* __restrict__ tdb,
    __hip_bfloat16* __restrict__ wob,
    _Float16* __restrict__ ku16, _Float16* __restrict__ vu16)
{
  int i = blockIdx.x * 256 + threadIdx.x;
  if (i < 2097152) {
    if (i < 1048576) xb[i] = __float2bfloat16(x[i]);
    else sbb[i - 1048576] = __float2bfloat16(sb[i - 1048576]);
  } else if (i < 3407872) {
    int j = i - 2097152;
    int w = j >> 18;
    int r = j & 262143;
    const float* s = (w == 0) ? wq : (w == 1) ? wk : (w == 2) ? wv : (w == 3) ? td : wo;
    __hip_bfloat16* d = (w == 0) ? wqb : (w == 1) ? wkb : (w == 2) ? wvb : (w == 3) ? tdb : wob;
    d[r] = __float2bfloat16(s[r]);
  } else if (i < 3473408) {
    // zero u16 margins: 2 arrays x 512 rows x 64 chunks of 8 f16 (16B)
    int t = i - 3407872;
    int arr = t >> 15;
    int rem = t & 32767;
    int row = rem >> 6;
    int cc = rem & 63;
    int col = (cc < 32) ? cc * 8 : 2304 + (cc - 32) * 8;
    _Float16* base = arr ? vu16 : ku16;
    *(int4*)(base + (size_t)row * UPAD + col) = int4{0, 0, 0, 0};
  }
}

// ---------------- batched GEMM: q,k,v,filters; l2norm + f16 pad-write for k,v ----------------
__global__ __launch_bounds__(256) void gemm4_kernel(
    const __hip_bfloat16* __restrict__ xb, const __hip_bfloat16* __restrict__ sbb,
    const __hip_bfloat16* __restrict__ wqb, const __hip_bfloat16* __restrict__ wkb,
    const __hip_bfloat16* __restrict__ wvb, const __hip_bfloat16* __restrict__ tdb,
    const float* __restrict__ bq, const float* __restrict__ bk,
    const float* __restrict__ bv, const float* __restrict__ btd,
    float* __restrict__ qout, float* __restrict__ fT,
    _Float16* __restrict__ ku16, _Float16* __restrict__ vu16)
{
  int z = blockIdx.z;
  const __hip_bfloat16* A = (z == 3) ? sbb : xb;
  const __hip_bfloat16* W = (z == 0) ? wqb : (z == 1) ? wkb : (z == 2) ? wvb : tdb;
  const float* bias = (z == 0) ? bq : (z == 1) ? bk : (z == 2) ? bv : btd;
  const int M = L_SEQ, N = D_MODEL, K = D_MODEL;
  int lane = threadIdx.x & 63;
  int wave = threadIdx.x >> 6;
  int m0 = blockIdx.x * 64 + wave * 16;
  int n0 = blockIdx.y * 64;
  int lrow = lane & 15, quad = lane >> 4;
  const __hip_bfloat16* Ap = A + (size_t)(m0 + lrow) * K + quad * 8;
  const __hip_bfloat16* Wp = W + (size_t)(n0 + lrow) * K + quad * 8;
  f32x4 acc[4] = {};
  for (int k0 = 0; k0 < K; k0 += 32) {
    short8 a = *(const short8*)(Ap + k0);
#pragma unroll
    for (int j = 0; j < 4; ++j) {
      short8 b = *(const short8*)(Wp + k0 + (size_t)j * 16 * K);
      acc[j] = __builtin_amdgcn_mfma_f32_16x16x32_bf16(a, b, acc[j], 0, 0, 0);
    }
  }
  float bw[4];
#pragma unroll
  for (int j = 0; j < 4; ++j) bw[j] = bias[n0 + j * 16 + lrow];
  if (z == 0) {
#pragma unroll
    for (int j = 0; j < 4; ++j)
#pragma unroll
      for (int r = 0; r < 4; ++r)
        qout[(size_t)(m0 + quad * 4 + r) * N + n0 + j * 16 + lrow] = acc[j][r] + bw[j];
  } else if (z == 3) {
#pragma unroll
    for (int j = 0; j < 4; ++j) {
      float4 ov = {acc[j][0] + bw[j], acc[j][1] + bw[j], acc[j][2] + bw[j], acc[j][3] + bw[j]};
      *(float4*)(fT + (size_t)(n0 + j * 16 + lrow) * M + m0 + quad * 4) = ov;
    }
  } else {
    float val[4][4];
#pragma unroll
    for (int j = 0; j < 4; ++j)
#pragma unroll
      for (int r = 0; r < 4; ++r) val[j][r] = acc[j][r] + bw[j];
    // l2-normalize over head dim (this block's 64 n-cols = one head)
    float pr[4];
#pragma unroll
    for (int r = 0; r < 4; ++r)
      pr[r] = val[0][r] * val[0][r] + val[1][r] * val[1][r] +
              val[2][r] * val[2][r] + val[3][r] * val[3][r];
#pragma unroll
    for (int off = 1; off < 16; off <<= 1)
#pragma unroll
      for (int r = 0; r < 4; ++r)
        pr[r] += __shfl_xor(pr[r], off, 64);
    _Float16* u16 = (z == 1) ? ku16 : vu16;
#pragma unroll
    for (int r = 0; r < 4; ++r) {
      float inv = 1.f / fmaxf(sqrtf(pr[r]), EPSF);
#pragma unroll
      for (int j = 0; j < 4; ++j) val[j][r] *= inv;
    }
#pragma unroll
    for (int j = 0; j < 4; ++j) {
      half4v pk = {(_Float16)val[j][0], (_Float16)val[j][1],
                   (_Float16)val[j][2], (_Float16)val[j][3]};
      *(half4v*)(u16 + (size_t)(n0 + j * 16 + lrow) * UPAD + UOFF + m0 + quad * 4) = pk;
    }
  }
}

// ---------------- causal conv via MFMA Toeplitz, filter in LDS (f16) ----------------
// block = 1 channel, 4 waves; wave = tile-pair {l0, 1792-l0}, BOTH tensors.
// A[m][k] = F[d+m-k] (d = l0+256-32i) read from 8-phase reversed LDS copies (b128);
// B[k][n] = u[s0+k+16n] f16 contiguous 16B/lane global. 4 MFMAs/step (k,v x hi,lo tile).
__global__ __launch_bounds__(256) void conv_kernel(
    const _Float16* __restrict__ ku16, const _Float16* __restrict__ vu16,
    const float* __restrict__ fT, float* __restrict__ oK, float* __restrict__ oV)
{
  __shared__ _Float16 lds_f[8 * XPAD];
  int c = blockIdx.x;
  int tid = threadIdx.x;
  const float* Fc = fT + (size_t)c * L_SEQ;
  // stage: lds_f[p][x] = f16(F[2063 - x - p]), zero outside [0,2048)
#pragma unroll
  for (int p = 0; p < 8; ++p) {
#pragma unroll
    for (int t = 0; t < 9; ++t) {
      int xx = tid + t * 256;
      if (xx < XLEN) {
        int j = 2063 - xx - p;
        float v = (j >= 0 && j < L_SEQ) ? Fc[j] : 0.f;
        lds_f[p * XPAD + xx] = (_Float16)v;
      }
    }
  }
  __syncthreads();

  int wave = tid >> 6, lane = tid & 63;
  int pair = wave;
  int l0_lo = 256 * pair;
  int l0_hi = 1792 - l0_lo;
  int mn = lane & 15, quad = lane >> 4;

  const _Float16* puk = ku16 + (size_t)c * UPAD + 16 * mn + 8 * quad;
  const _Float16* puv = vu16 + (size_t)c * UPAD + 16 * mn + 8 * quad;

  int j0c = 2063 - mn;
  int p8 = j0c & 7;
  int xb0 = (j0c - p8) + 8 * quad;
  const _Float16* pf_hi = lds_f + p8 * XPAD + (xb0 - (l0_hi + 256));
  const _Float16* pf_lo = lds_f + p8 * XPAD + (xb0 - (l0_lo + 256));

  int steps_lo = pair * 8 + 9;
  int steps_hi = 65 - pair * 8;
  f32x4 ak_hi = {}, ak_lo = {}, av_hi = {}, av_lo = {};
#pragma unroll 2
  for (int i = 0; i < steps_lo; ++i) {
    half8 bk = *(const half8*)puk;
    half8 bv = *(const half8*)puv;
    half8 fh = *(const half8*)pf_hi;
    half8 fl = *(const half8*)pf_lo;
    puk += 32; puv += 32; pf_hi += 32; pf_lo += 32;
    ak_hi = __builtin_amdgcn_mfma_f32_16x16x32_f16(fh, bk, ak_hi, 0, 0, 0);
    av_hi = __builtin_amdgcn_mfma_f32_16x16x32_f16(fh, bv, av_hi, 0, 0, 0);
    ak_lo = __builtin_amdgcn_mfma_f32_16x16x32_f16(fl, bk, ak_lo, 0, 0, 0);
    av_lo = __builtin_amdgcn_mfma_f32_16x16x32_f16(fl, bv, av_lo, 0, 0, 0);
  }
#pragma unroll 2
  for (int i = steps_lo; i < steps_hi; ++i) {
    half8 bk = *(const half8*)puk;
    half8 bv = *(const half8*)puv;
    half8 fh = *(const half8*)pf_hi;
    puk += 32; puv += 32; pf_hi += 32;
    ak_hi = __builtin_amdgcn_mfma_f32_16x16x32_f16(fh, bk, ak_hi, 0, 0, 0);
    av_hi = __builtin_amdgcn_mfma_f32_16x16x32_f16(fh, bv, av_hi, 0, 0, 0);
  }
  size_t ob = (size_t)c * L_SEQ + 16 * mn + 4 * quad;
  *(float4*)(oK + ob + l0_hi) = float4{ak_hi[0], ak_hi[1], ak_hi[2], ak_hi[3]};
  *(float4*)(oK + ob + l0_lo) = float4{ak_lo[0], ak_lo[1], ak_lo[2], ak_lo[3]};
  *(float4*)(oV + ob + l0_hi) = float4{av_hi[0], av_hi[1], av_hi[2], av_hi[3]};
  *(float4*)(oV + ob + l0_lo) = float4{av_lo[0], av_lo[1], av_lo[2], av_lo[3]};
}

// ---------------- fused gate + partials per (h, chunk) ----------------
__global__ __launch_bounds__(256) void gatepart_kernel(const float* __restrict__ kf,
    const float* __restrict__ vf, const float* __restrict__ wgz_w,
    const float* __restrict__ wgz_b, const float* __restrict__ kvs,
    float* __restrict__ g, float* __restrict__ A, float* __restrict__ gsum)
{
  __shared__ float MT[64][68];
  __shared__ float kb[64][68];
  __shared__ float vb[64][68];
  __shared__ float yb[64][68];
  __shared__ float part[4][64];
  __shared__ float gl[64];
  int h = blockIdx.y, ch = blockIdx.x;
  int t0 = ch * 64, tid = threadIdx.x;
#pragma unroll
  for (int k = 0; k < 16; ++k) {
    int idx = tid + k * 256;
    int a = idx >> 6, b = idx & 63;
    MT[b][a] = wgz_w[idx] * kvs[idx];
    kb[a][b] = kf[(size_t)(h * 64 + a) * L_SEQ + t0 + b];
    vb[a][b] = vf[(size_t)(h * 64 + a) * L_SEQ + t0 + b];
  }
  __syncthreads();
  int lg = tid & 15, dg = tid >> 4;
  {
    float acc[4][4] = {};
    for (int e = 0; e < 64; ++e) {
      float4 mv4 = *(const float4*)(&MT[e][dg * 4]);
      float4 kv4 = *(const float4*)(&kb[e][lg * 4]);
      float mvv[4] = {mv4.x, mv4.y, mv4.z, mv4.w};
      float kvv[4] = {kv4.x, kv4.y, kv4.z, kv4.w};
#pragma unroll
      for (int r = 0; r < 4; ++r)
#pragma unroll
        for (int j = 0; j < 4; ++j)
          acc[r][j] = fmaf(mvv[r], kvv[j], acc[r][j]);
    }
#pragma unroll
    for (int r = 0; r < 4; ++r)
#pragma unroll
      for (int j = 0; j < 4; ++j)
        yb[dg * 4 + r][lg * 4 + j] = acc[r][j];
  }
  __syncthreads();
  {
    int l = tid & 63, p = tid >> 6;
    float s = 0.f;
#pragma unroll
    for (int dd = 0; dd < 16; ++dd)
      s = fmaf(yb[p * 16 + dd][l], vb[p * 16 + dd][l], s);
    part[p][l] = s;
  }
  __syncthreads();
  if (tid < 64) {
    float logit = part[0][tid] + part[1][tid] + part[2][tid] + part[3][tid] + wgz_b[0];
    float rl = fmaxf(logit, 0.f);
    float gv = rl * rl + EPSF;
    g[h * L_SEQ + t0 + tid] = gv;
    gl[tid] = gv;
  }
  __syncthreads();
  int eg = tid & 15, dg2 = tid >> 4;
  float acc[4][4] = {};
  for (int t = 0; t < 64; ++t) {
    float gt = gl[t];
    float kv4[4], vv4[4];
#pragma unroll
    for (int j = 0; j < 4; ++j) kv4[j] = kb[eg * 4 + j][t] * gt;
#pragma unroll
    for (int r = 0; r < 4; ++r) vv4[r] = vb[dg2 * 4 + r][t];
#pragma unroll
    for (int r = 0; r < 4; ++r)
#pragma unroll
      for (int j = 0; j < 4; ++j)
        acc[r][j] = fmaf(vv4[r], kv4[j], acc[r][j]);
  }
  float* Ap = A + ((size_t)(h * 32 + ch)) * 4096;
#pragma unroll
  for (int r = 0; r < 4; ++r)
#pragma unroll
    for (int j = 0; j < 4; ++j)
      Ap[(dg2 * 4 + r) * 64 + eg * 4 + j] = acc[r][j];
  if (tid == 0) {
    float s = 0.f;
    for (int t = 0; t < 64; ++t) s += gl[t];
    gsum[h * 32 + ch] = s;
  }
}

// ---------------- exclusive prefix over 32 chunks (in place) ----------------
__global__ void prefix_kernel(float* __restrict__ A, float* __restrict__ gsum)
{
  int flat = blockIdx.x * 256 + threadIdx.x;
  int h = flat >> 12, de = flat & 4095;
  float run = 0.f;
  for (int c = 0; c < 32; ++c) {
    size_t idx = ((size_t)(h * 32 + c)) * 4096 + de;
    float t = A[idx];
    A[idx] = run;
    run += t;
  }
  if (flat < 8) {
    float r = 0.f;
    for (int c = 0; c < 32; ++c) { float t = gsum[flat * 32 + c]; gsum[flat * 32 + c] = r; r += t; }
  }
}

// ---------------- attention: carry + in-chunk gated quadratic, /G, l2norm, bf16 store ----------------
__global__ __launch_bounds__(256) void attn_kernel(const float* __restrict__ q,
    const float* __restrict__ kf, const float* __restrict__ vf, const float* __restrict__ g,
    const float* __restrict__ Sprev, const float* __restrict__ Gprev,
    __hip_bfloat16* __restrict__ sp)
{
  __shared__ float qT[64][68];
  __shared__ float SW[64][69];
  __shared__ float vb[64][68];
  __shared__ float kb[64][69];
  __shared__ float gl[64], Gs[64], rsq[64];
  int h = blockIdx.y, ch = blockIdx.x;
  int t0 = ch * 64, tid = threadIdx.x;
  const float* Sp = Sprev + ((size_t)(h * 32 + ch)) * 4096;
#pragma unroll
  for (int k = 0; k < 16; ++k) {
    int idx = tid + k * 256;
    int a = idx >> 6, b = idx & 63;
    qT[b][a] = q[(size_t)(t0 + a) * D_MODEL + h * 64 + b];
    SW[a][b] = Sp[idx];
    vb[a][b] = vf[(size_t)(h * 64 + a) * L_SEQ + t0 + b];
    kb[a][b] = kf[(size_t)(h * 64 + a) * L_SEQ + t0 + b];
  }
  if (tid < 64) { gl[tid] = g[h * L_SEQ + t0 + tid]; rsq[tid] = 0.f; }
  __syncthreads();
  if (tid < 64) {
    float val = gl[tid];
#pragma unroll
    for (int off = 1; off < 64; off <<= 1) {
      float o = __shfl_up(val, (unsigned)off, 64);
      if (tid >= off) val += o;
    }
    Gs[tid] = fmaxf(Gprev[h * 32 + ch] + val, EPSF);
  }
  int lg = tid & 15, eg = tid >> 4;
  float acc[4][4] = {};
  for (int d = 0; d < 64; ++d) {
    float4 q4 = *(const float4*)(&qT[d][lg * 4]);
    float qv[4] = {q4.x, q4.y, q4.z, q4.w};
    float sv[4];
#pragma unroll
    for (int j = 0; j < 4; ++j) sv[j] = SW[d][eg * 4 + j];
#pragma unroll
    for (int r = 0; r < 4; ++r)
#pragma unroll
      for (int j = 0; j < 4; ++j)
        acc[r][j] = fmaf(qv[r], sv[j], acc[r][j]);
  }
  __syncthreads();
  float sc[4][4] = {};
  for (int d = 0; d < 64; ++d) {
    float4 q4 = *(const float4*)(&qT[d][lg * 4]);
    float4 v4 = *(const float4*)(&vb[d][eg * 4]);
    float qv[4] = {q4.x, q4.y, q4.z, q4.w};
    float vv[4] = {v4.x, v4.y, v4.z, v4.w};
#pragma unroll
    for (int r = 0; r < 4; ++r)
#pragma unroll
      for (int m = 0; m < 4; ++m)
        sc[r][m] = fmaf(qv[r], vv[m], sc[r][m]);
  }
#pragma unroll
  for (int r = 0; r < 4; ++r)
#pragma unroll
    for (int m = 0; m < 4; ++m) {
      int ll = lg * 4 + r, tt = eg * 4 + m;
      SW[ll][tt] = (tt <= ll) ? sc[r][m] * gl[tt] : 0.f;
    }
  __syncthreads();
  for (int t = 0; t < 64; ++t) {
    float wv4[4], kv4[4];
#pragma unroll
    for (int r = 0; r < 4; ++r) wv4[r] = SW[lg * 4 + r][t];
#pragma unroll
    for (int j = 0; j < 4; ++j) kv4[j] = kb[eg * 4 + j][t];
#pragma unroll
    for (int r = 0; r < 4; ++r)
#pragma unroll
      for (int j = 0; j < 4; ++j)
        acc[r][j] = fmaf(wv4[r], kv4[j], acc[r][j]);
  }
  float val[4][4];
#pragma unroll
  for (int r = 0; r < 4; ++r) {
    float gi = 1.f / Gs[lg * 4 + r];
    float pr = 0.f;
#pragma unroll
    for (int j = 0; j < 4; ++j) { float v = acc[r][j] * gi; val[r][j] = v; pr = fmaf(v, v, pr); }
    atomicAdd(&rsq[lg * 4 + r], pr);
  }
  __syncthreads();
#pragma unroll
  for (int r = 0; r < 4; ++r) {
    float inv = 1.f / fmaxf(sqrtf(rsq[lg * 4 + r]), EPSF);
    union { ushort4 u; __hip_bfloat16 hh[4]; } pk;
#pragma unroll
    for (int j = 0; j < 4; ++j) pk.hh[j] = __float2bfloat16(val[r][j] * inv);
    *(ushort4*)(sp + (size_t)(t0 + lg * 4 + r) * D_MODEL + h * 64 + eg * 4) = pk.u;
  }
}

// ---------------- final GEMM: out = sp @ wo^T + b ----------------
__global__ __launch_bounds__(256) void gemm_out_kernel(const __hip_bfloat16* __restrict__ A,
    const __hip_bfloat16* __restrict__ W, const float* __restrict__ bias,
    float* __restrict__ O)
{
  const int N = D_MODEL, K = D_MODEL;
  int lane = threadIdx.x & 63;
  int wave = threadIdx.x >> 6;
  int m0 = blockIdx.x * 64 + wave * 16;
  int n0 = blockIdx.y * 64;
  int lrow = lane & 15, quad = lane >> 4;
  const __hip_bfloat16* Ap = A + (size_t)(m0 + lrow) * K + quad * 8;
  const __hip_bfloat16* Wp = W + (size_t)(n0 + lrow) * K + quad * 8;
  f32x4 acc[4] = {};
  for (int k0 = 0; k0 < K; k0 += 32) {
    short8 a = *(const short8*)(Ap + k0);
#pragma unroll
    for (int j = 0; j < 4; ++j) {
      short8 b = *(const short8*)(Wp + k0 + (size_t)j * 16 * K);
      acc[j] = __builtin_amdgcn_mfma_f32_16x16x32_bf16(a, b, acc[j], 0, 0, 0);
    }
  }
#pragma unroll
  for (int j = 0; j < 4; ++j) {
    int n = n0 + j * 16 + lrow;
    float bv = bias[n];
#pragma unroll
    for (int r = 0; r < 4; ++r)
      O[(size_t)(m0 + quad * 4 + r) * N + n] = acc[j][r] + bv;
  }
}

extern "C" void kernel_launch(void* const* d_in, const int* in_sizes, int n_in,
                              void* d_out, int out_size, void* d_ws, size_t ws_size,
                              hipStream_t stream) {
  const float* x = (const float*)d_in[0];
  const float* sb = (const float*)d_in[1];
  const float* wq_w = (const float*)d_in[2];
  const float* wq_b = (const float*)d_in[3];
  const float* wk_w = (const float*)d_in[4];
  const float* wk_b = (const float*)d_in[5];
  const float* wv_w = (const float*)d_in[6];
  const float* wv_b = (const float*)d_in[7];
  const float* wo_w = (const float*)d_in[8];
  const float* wo_b = (const float*)d_in[9];
  const float* td_w = (const float*)d_in[10];
  const float* td_b = (const float*)d_in[11];
  const float* wgz_w = (const float*)d_in[12];
  const float* wgz_b = (const float*)d_in[13];
  const float* kvs = (const float*)d_in[14];
  float* out = (float*)d_out;

  char* ws = (char*)d_ws;
  size_t off = 0;
  auto alloc = [&](size_t bytes) -> void* {
    void* p = ws + off;
    off += (bytes + 255) & ~(size_t)255;
    return p;
  };
  __hip_bfloat16* xb  = (__hip_bfloat16*)alloc((size_t)L_SEQ * D_MODEL * 2);
  __hip_bfloat16* sbb = (__hip_bfloat16*)alloc((size_t)L_SEQ * D_MODEL * 2);
  __hip_bfloat16* wqb = (__hip_bfloat16*)alloc((size_t)D_MODEL * D_MODEL * 2);
  __hip_bfloat16* wkb = (__hip_bfloat16*)alloc((size_t)D_MODEL * D_MODEL * 2);
  __hip_bfloat16* wvb = (__hip_bfloat16*)alloc((size_t)D_MODEL * D_MODEL * 2);
  __hip_bfloat16* tdb = (__hip_bfloat16*)alloc((size_t)D_MODEL * D_MODEL * 2);
  __hip_bfloat16* wob = (__hip_bfloat16*)alloc((size_t)D_MODEL * D_MODEL * 2);
  __hip_bfloat16* spb = (__hip_bfloat16*)alloc((size_t)L_SEQ * D_MODEL * 2);
  _Float16* ku16 = (_Float16*)alloc((size_t)D_MODEL * UPAD * 2);
  _Float16* vu16 = (_Float16*)alloc((size_t)D_MODEL * UPAD * 2);
  float* qbuf  = (float*)alloc((size_t)L_SEQ * D_MODEL * 4);
  float* fT    = (float*)alloc((size_t)D_MODEL * L_SEQ * 4);
  float* kfT   = (float*)alloc((size_t)D_MODEL * L_SEQ * 4);
  float* vfT   = (float*)alloc((size_t)D_MODEL * L_SEQ * 4);
  float* gbuf  = (float*)alloc((size_t)NH * L_SEQ * 4);
  float* gsum  = (float*)alloc((size_t)NH * 32 * 4);
  float* Abuf  = (float*)alloc((size_t)NH * 32 * 4096 * 4);

  prep_kernel<<<13568, 256, 0, stream>>>(x, sb, wq_w, wk_w, wv_w, td_w, wo_w,
                                         xb, sbb, wqb, wkb, wvb, tdb, wob,
                                         ku16, vu16);
  gemm4_kernel<<<dim3(L_SEQ / 64, D_MODEL / 64, 4), 256, 0, stream>>>(
      xb, sbb, wqb, wkb, wvb, tdb, wq_b, wk_b, wv_b, td_b, qbuf, fT,
      ku16, vu16);
  conv_kernel<<<512, 256, 0, stream>>>(ku16, vu16, fT, kfT, vfT);
  gatepart_kernel<<<dim3(32, 8), 256, 0, stream>>>(kfT, vfT, wgz_w, wgz_b, kvs, gbuf, Abuf, gsum);
  prefix_kernel<<<128, 256, 0, stream>>>(Abuf, gsum);
  attn_kernel<<<dim3(32, 8), 256, 0, stream>>>(qbuf, kfT, vfT, gbuf, Abuf, gsum, spb);
  gemm_out_kernel<<<dim3(L_SEQ / 64, D_MODEL / 64), 256, 0, stream>>>(spb, wob, wo_b, out);
}